// Round 1
// baseline (924.774 us; speedup 1.0000x reference)
//
#include <hip/hip_runtime.h>
#include <float.h>

// ---------------------------------------------------------------------------
// VQ layer forward, MI355X. Sizes fixed: B=4, L=2048 (8192 tokens), D=1024,
// VQ_DIM=64, K_CODES=8192, EMA_K=5.
// Outputs (f32, concatenated): q_out[8388608], code[8192], vq_loss[1],
// new_emb[524288], new_count[8192].
// ---------------------------------------------------------------------------

// ---------------- Kernel 1: hp = normalize(h @ proj_w + b) -----------------
// 8 tokens per block, 256 threads. Each thread = (dim 0..63, part 0..3).
__global__ __launch_bounds__(256) void k_proj(
    const float* __restrict__ h, const float* __restrict__ w,
    const float* __restrict__ bias,
    float* __restrict__ hp_norm, float* __restrict__ h2) {
  __shared__ float hs[8 * 1024];
  __shared__ float red[256][9];   // pad 9 to break bank stride
  __shared__ float hpv[8][64];
  const int tb = blockIdx.x * 8;
  const int tid = threadIdx.x;
  {
    const float4* h4 = (const float4*)(h + (size_t)tb * 1024);
    float4* hs4 = (float4*)hs;
#pragma unroll
    for (int i = 0; i < 8; ++i) hs4[tid + 256 * i] = h4[tid + 256 * i];
  }
  __syncthreads();
  const int dim = tid & 63;
  const int part = tid >> 6;
  float acc[8];
#pragma unroll
  for (int t = 0; t < 8; ++t) acc[t] = 0.f;
  for (int k = part; k < 1024; k += 4) {
    float wv = w[k * 64 + dim];   // coalesced 256B per wave
#pragma unroll
    for (int t = 0; t < 8; ++t) acc[t] = fmaf(hs[t * 1024 + k], wv, acc[t]);
  }
#pragma unroll
  for (int t = 0; t < 8; ++t) red[tid][t] = acc[t];
  __syncthreads();
#pragma unroll
  for (int i = 0; i < 2; ++i) {
    int idx = tid + i * 256;
    int t = idx >> 6, d = idx & 63;
    float s = red[d][t] + red[d + 64][t] + red[d + 128][t] + red[d + 192][t];
    hpv[t][d] = s + bias[d];
  }
  __syncthreads();
  const int wid = tid >> 6;
  const int lane = tid & 63;
#pragma unroll
  for (int t0 = 0; t0 < 2; ++t0) {
    int t = wid + t0 * 4;
    float v = hpv[t][lane];
    float sq = v * v;
#pragma unroll
    for (int o = 32; o > 0; o >>= 1) sq += __shfl_xor(sq, o, 64);
    float vn = v / sqrtf(sq);
    hp_norm[(size_t)(tb + t) * 64 + lane] = vn;
    float s2 = vn * vn;          // reference recomputes sum(h_flat^2) on the
#pragma unroll                   // normalized values; mimic that exactly
    for (int o = 32; o > 0; o >>= 1) s2 += __shfl_xor(s2, o, 64);
    if (lane == 0) h2[tb + t] = s2;
  }
}

// ---------------- Kernel 2: E = normalize(emb), e2 = sum(E^2) --------------
__global__ __launch_bounds__(256) void k_enorm(
    const float* __restrict__ emb, float* __restrict__ E,
    float* __restrict__ e2) {
  const int c = blockIdx.x * 4 + (threadIdx.x >> 6);
  const int lane = threadIdx.x & 63;
  float v = emb[(size_t)c * 64 + lane];
  float sq = v * v;
#pragma unroll
  for (int o = 32; o > 0; o >>= 1) sq += __shfl_xor(sq, o, 64);
  float vn = v / sqrtf(sq);
  E[(size_t)c * 64 + lane] = vn;
  float s2 = vn * vn;
#pragma unroll
  for (int o = 32; o > 0; o >>= 1) s2 += __shfl_xor(s2, o, 64);
  if (lane == 0) e2[c] = s2;
}

// ---------------- Kernel 3: distance tiles, argmin partials, top5 partials -
// Block = 128 tokens x 1024 codes (grid 64 x 8). 16 chunks of 64 codes.
// dist = h2[t] + e2[c] - 2*dot, then mask: dist*m + 1e7*(1-m).
__global__ __launch_bounds__(256) void k_dist(
    const float* __restrict__ hp, const float* __restrict__ h2g,
    const float* __restrict__ Eg, const float* __restrict__ e2g,
    const float* __restrict__ maskg,
    float* __restrict__ amin_d, int* __restrict__ amin_c,
    float* __restrict__ t5d, int* __restrict__ t5i) {
  __shared__ float hs[128 * 68];   // pad 68: float4-aligned rows
  __shared__ float es[64 * 68];
  __shared__ float dsh[128 * 65];  // pad 65: conflict-free scalar scans
  __shared__ float h2s[128], msk[128], e2s[64];
  const int tid = threadIdx.x;
  const int tb = blockIdx.x * 128;
  const int cs0 = blockIdx.y * 1024;
#pragma unroll
  for (int i = 0; i < 32; ++i) {
    int idx = tid + i * 256;
    int t = idx >> 6, j = idx & 63;
    hs[t * 68 + j] = hp[(size_t)(tb + t) * 64 + j];
  }
  if (tid < 128) {
    h2s[tid] = h2g[tb + tid];
    msk[tid] = maskg[tb + tid];
  }
  float bestd = FLT_MAX;
  int bestc = 0x7fffffff;
  const int gt = tid >> 4;   // 16 token groups of 8
  const int gc = tid & 15;   // 16 code groups of 4
  for (int ch = 0; ch < 16; ++ch) {
    const int cb = cs0 + ch * 64;
    __syncthreads();  // staging done / previous scans done
    for (int i = 0; i < 16; ++i) {
      int idx = tid + i * 256;
      int c = idx >> 6, j = idx & 63;
      es[c * 68 + j] = Eg[(size_t)(cb + c) * 64 + j];
    }
    if (tid < 64) e2s[tid] = e2g[cb + tid];
    __syncthreads();
    float acc[8][4];
#pragma unroll
    for (int i = 0; i < 8; ++i)
#pragma unroll
      for (int j = 0; j < 4; ++j) acc[i][j] = 0.f;
    for (int k4 = 0; k4 < 16; ++k4) {
      float4 av[8], bv[4];
#pragma unroll
      for (int i = 0; i < 8; ++i)
        av[i] = *(const float4*)&hs[(gt * 8 + i) * 68 + k4 * 4];
#pragma unroll
      for (int j = 0; j < 4; ++j)
        bv[j] = *(const float4*)&es[(gc * 4 + j) * 68 + k4 * 4];
#pragma unroll
      for (int i = 0; i < 8; ++i)
#pragma unroll
        for (int j = 0; j < 4; ++j) {
          float s = acc[i][j];
          s = fmaf(av[i].x, bv[j].x, s);
          s = fmaf(av[i].y, bv[j].y, s);
          s = fmaf(av[i].z, bv[j].z, s);
          s = fmaf(av[i].w, bv[j].w, s);
          acc[i][j] = s;
        }
    }
#pragma unroll
    for (int i = 0; i < 8; ++i) {
      int t = gt * 8 + i;
      float mt = msk[t];
      float h2v = h2s[t];
#pragma unroll
      for (int j = 0; j < 4; ++j) {
        int c = gc * 4 + j;
        float dist = h2v + e2s[c] - 2.f * acc[i][j];
        dist = dist * mt + 1.0e7f * (1.f - mt);
        dsh[t * 65 + c] = dist;
      }
    }
    __syncthreads();
    if (tid < 128) {
      // per-token argmin over this chunk (running across chunks in regs)
      const int t = tid;
      for (int c = 0; c < 64; ++c) {
        float d = dsh[t * 65 + c];
        if (d < bestd) { bestd = d; bestc = cb + c; }  // strict < : lowest code wins ties
      }
    } else if (tid < 192) {
      // per-code top-5 of the 128 tokens; scan order ascending token idx so
      // strict < preserves lax.top_k's stable tie-breaking.
      const int c = tid - 128;
      float d0 = FLT_MAX, d1 = FLT_MAX, d2 = FLT_MAX, d3 = FLT_MAX, d4 = FLT_MAX;
      int i0 = 0, i1 = 0, i2 = 0, i3 = 0, i4 = 0;
      for (int t = 0; t < 128; ++t) {
        float d = dsh[t * 65 + c];
        if (d < d4) {
          d4 = d; i4 = tb + t;
          if (d4 < d3) { float td=d3; d3=d4; d4=td; int ti=i3; i3=i4; i4=ti; }
          if (d3 < d2) { float td=d2; d2=d3; d3=td; int ti=i2; i2=i3; i3=ti; }
          if (d2 < d1) { float td=d1; d1=d2; d2=td; int ti=i1; i1=i2; i2=ti; }
          if (d1 < d0) { float td=d0; d0=d1; d1=td; int ti=i0; i0=i1; i1=ti; }
        }
      }
      size_t base = (size_t)(cb + c) * 320 + (size_t)blockIdx.x * 5;
      t5d[base + 0] = d0; t5i[base + 0] = i0;
      t5d[base + 1] = d1; t5i[base + 1] = i1;
      t5d[base + 2] = d2; t5i[base + 2] = i2;
      t5d[base + 3] = d3; t5i[base + 3] = i3;
      t5d[base + 4] = d4; t5i[base + 4] = i4;
    }
  }
  if (tid < 128) {
    int t = tb + tid;
    amin_d[(size_t)t * 8 + blockIdx.y] = bestd;
    amin_c[(size_t)t * 8 + blockIdx.y] = bestc;
  }
}

// ---------------- init new_count = count ------------------------------------
__global__ void k_initcount(const float* __restrict__ cnt,
                            float* __restrict__ ncnt) {
  int i = blockIdx.x * 256 + threadIdx.x;
  ncnt[i] = cnt[i];
}

// ---------------- Kernel 4: merge argmin, code, histogram, per-token loss --
__global__ __launch_bounds__(256) void k_code(
    const float* __restrict__ amin_d, const int* __restrict__ amin_c,
    const float* __restrict__ hp, const float* __restrict__ E,
    float* __restrict__ code_f, int* __restrict__ code_i,
    float* __restrict__ newcount, float* __restrict__ loss_tok) {
  const int wid = threadIdx.x >> 6;
  const int lane = threadIdx.x & 63;
  const int t = blockIdx.x * 4 + wid;
  float d = FLT_MAX;
  int c = 0x7fffffff;
  if (lane < 8) {
    d = amin_d[(size_t)t * 8 + lane];
    c = amin_c[(size_t)t * 8 + lane];
  }
#pragma unroll
  for (int o = 4; o > 0; o >>= 1) {
    float od = __shfl_xor(d, o, 64);
    int oc = __shfl_xor(c, o, 64);
    if (od < d || (od == d && oc < c)) { d = od; c = oc; }
  }
  c = __shfl(c, 0, 64);
  // loss = 1.25 * huber(hp, q_ste); q_ste forward = hp + (E[c]-hp)
  float a = hp[(size_t)t * 64 + lane];
  float e = E[(size_t)c * 64 + lane];
  float q = a + (e - a);
  float df = a - q;
  float ad = fabsf(df);
  float l = ad < 1.f ? 0.5f * df * df : ad - 0.5f;
#pragma unroll
  for (int o = 32; o > 0; o >>= 1) l += __shfl_xor(l, o, 64);
  if (lane == 0) {
    code_f[t] = (float)c;
    code_i[t] = c;
    loss_tok[t] = l;                 // unmasked; mask applied at final reduce
    atomicAdd(&newcount[c], 1.0f);   // integer-valued f32 adds: exact, order-free
  }
}

// ---------------- Kernel 5: q_out = q_ste @ proj_inv_w + b -----------------
// 16 tokens per block; each thread owns 4 consecutive output dims.
__global__ __launch_bounds__(256) void k_qout(
    const int* __restrict__ code_i, const float* __restrict__ hp,
    const float* __restrict__ E, const float* __restrict__ w,
    const float* __restrict__ bias, float* __restrict__ qout) {
  __shared__ float qs[16][64];
  const int tid = threadIdx.x;
  const int tb = blockIdx.x * 16;
#pragma unroll
  for (int i = 0; i < 4; ++i) {
    int idx = tid + i * 256;
    int t = idx >> 6, j = idx & 63;
    int c = code_i[tb + t];
    float a = hp[(size_t)(tb + t) * 64 + j];
    float e = E[(size_t)c * 64 + j];
    qs[t][j] = a + (e - a);
  }
  __syncthreads();
  float acc[16][4];
#pragma unroll
  for (int t = 0; t < 16; ++t)
#pragma unroll
    for (int j = 0; j < 4; ++j) acc[t][j] = 0.f;
  const float4* w4 = (const float4*)w;
  for (int k = 0; k < 64; ++k) {
    float4 wv = w4[k * 256 + tid];
#pragma unroll
    for (int t = 0; t < 16; ++t) {
      float q = qs[t][k];   // LDS broadcast
      acc[t][0] = fmaf(q, wv.x, acc[t][0]);
      acc[t][1] = fmaf(q, wv.y, acc[t][1]);
      acc[t][2] = fmaf(q, wv.z, acc[t][2]);
      acc[t][3] = fmaf(q, wv.w, acc[t][3]);
    }
  }
  const float4 bv = ((const float4*)bias)[tid];
  float4* o4 = (float4*)qout;
#pragma unroll
  for (int t = 0; t < 16; ++t) {
    float4 r;
    r.x = acc[t][0] + bv.x; r.y = acc[t][1] + bv.y;
    r.z = acc[t][2] + bv.z; r.w = acc[t][3] + bv.w;
    o4[(size_t)(tb + t) * 256 + tid] = r;
  }
}

// ---------------- Kernel 6: merge top5, EMA update of embeddings -----------
// One wave per code; 64 lanes = 64 token-blocks, 5 candidates each.
__global__ __launch_bounds__(256) void k_emb(
    const float* __restrict__ t5d, const int* __restrict__ t5i,
    const float* __restrict__ hp, const float* __restrict__ E,
    float* __restrict__ newemb) {
  const int wid = threadIdx.x >> 6;
  const int lane = threadIdx.x & 63;
  const int c = blockIdx.x * 4 + wid;
  float cd[5]; int ci[5];
  size_t base = (size_t)c * 320 + (size_t)lane * 5;
#pragma unroll
  for (int s = 0; s < 5; ++s) { cd[s] = t5d[base + s]; ci[s] = t5i[base + s]; }
  bool chosen[5] = {false, false, false, false, false};
  int sel[5]; float seld[5];
#pragma unroll
  for (int r = 0; r < 5; ++r) {
    float bd = FLT_MAX; int bi = 0x7fffffff;
#pragma unroll
    for (int s = 0; s < 5; ++s) {
      bool better = !chosen[s] && (cd[s] < bd || (cd[s] == bd && ci[s] < bi));
      if (better) { bd = cd[s]; bi = ci[s]; }
    }
#pragma unroll
    for (int o = 32; o > 0; o >>= 1) {
      float od = __shfl_xor(bd, o, 64);
      int oi = __shfl_xor(bi, o, 64);
      if (od < bd || (od == bd && oi < bi)) { bd = od; bi = oi; }
    }
    sel[r] = bi; seld[r] = bd;
#pragma unroll
    for (int s = 0; s < 5; ++s) if (ci[s] == bi) chosen[s] = true;  // token ids unique
  }
  float m5 = fabsf(seld[0]);
#pragma unroll
  for (int r = 1; r < 5; ++r) m5 = fminf(m5, fabsf(seld[r]));
  float hf = 0.f;
#pragma unroll
  for (int r = 0; r < 5; ++r) hf += hp[(size_t)sel[r] * 64 + lane];
  hf = hf / 5.0f;
  float ev = E[(size_t)c * 64 + lane];
  float outv = (m5 > 0.1f) ? (ev * 0.995f + hf * (float)(1.0 - 0.995)) : ev;
  newemb[(size_t)c * 64 + lane] = outv;
}

// ---------------- Kernel 7: vq_loss = (1/256) * sum_b S_b/M_b * 1.25 --------
__global__ __launch_bounds__(256) void k_vq(
    const float* __restrict__ loss_tok, const float* __restrict__ maskg,
    float* __restrict__ vq) {
  __shared__ float S[256], M[256];
  const int tid = threadIdx.x;
  float s = 0.f, m = 0.f;
  const int base = tid * 32;   // 64 threads per batch (2048 tokens / 32)
  for (int i = 0; i < 32; ++i) {
    float mm = maskg[base + i];
    s = fmaf(loss_tok[base + i], mm, s);
    m += mm;
  }
  S[tid] = s; M[tid] = m;
  __syncthreads();
  if (tid == 0) {
    float tot = 0.f;
    for (int b = 0; b < 4; ++b) {
      float sb = 0.f, mb = 0.f;
      for (int i = 0; i < 64; ++i) { sb += S[b * 64 + i]; mb += M[b * 64 + i]; }
      tot += sb / mb;
    }
    vq[0] = tot * 1.25f / 256.0f;
  }
}

// ---------------------------------------------------------------------------
extern "C" void kernel_launch(void* const* d_in, const int* in_sizes, int n_in,
                              void* d_out, int out_size, void* d_ws,
                              size_t ws_size, hipStream_t stream) {
  (void)in_sizes; (void)n_in; (void)out_size; (void)ws_size;
  const float* h          = (const float*)d_in[0];
  const float* mask       = (const float*)d_in[1];
  const float* proj_w     = (const float*)d_in[2];
  const float* proj_b     = (const float*)d_in[3];
  const float* proj_inv_w = (const float*)d_in[4];
  const float* proj_inv_b = (const float*)d_in[5];
  const float* emb        = (const float*)d_in[6];
  const float* count      = (const float*)d_in[7];

  float* out      = (float*)d_out;
  float* q_out    = out;                 // 8388608
  float* code_f   = out + 8388608;       // 8192
  float* vq       = out + 8396800;       // 1
  float* newemb   = out + 8396801;       // 524288
  float* newcount = out + 8921089;       // 8192

  float* ws       = (float*)d_ws;
  float* hp_norm  = ws;                       // 524288
  float* h2       = ws + 524288;              // 8192
  float* E        = ws + 532480;              // 524288
  float* e2       = ws + 1056768;             // 8192
  float* amin_d   = ws + 1064960;             // 65536
  int*   amin_c   = (int*)(ws + 1130496);     // 65536
  int*   code_i   = (int*)(ws + 1196032);     // 8192
  float* t5d      = ws + 1204224;             // 2621440 (8192*64*5)
  int*   t5i      = (int*)(ws + 3825664);     // 2621440
  float* loss_tok = ws + 6447104;             // 8192  (total ~25.8 MB)

  k_proj<<<1024, 256, 0, stream>>>(h, proj_w, proj_b, hp_norm, h2);
  k_enorm<<<2048, 256, 0, stream>>>(emb, E, e2);
  k_dist<<<dim3(64, 8), 256, 0, stream>>>(hp_norm, h2, E, e2, mask,
                                          amin_d, amin_c, t5d, t5i);
  k_initcount<<<32, 256, 0, stream>>>(count, newcount);
  k_code<<<2048, 256, 0, stream>>>(amin_d, amin_c, hp_norm, E,
                                   code_f, code_i, newcount, loss_tok);
  k_qout<<<512, 256, 0, stream>>>(code_i, hp_norm, E, proj_inv_w, proj_inv_b,
                                  q_out);
  k_emb<<<2048, 256, 0, stream>>>(t5d, t5i, hp_norm, E, newemb);
  k_vq<<<1, 256, 0, stream>>>(loss_tok, mask, vq);
}

// Round 2
// 495.515 us; speedup vs baseline: 1.8663x; 1.8663x over previous
//
#include <hip/hip_runtime.h>
#include <float.h>

// ---------------------------------------------------------------------------
// VQ layer forward, MI355X. B=4, L=2048 (8192 tokens), D=1024, VQ_DIM=64,
// K_CODES=8192, EMA_K=5.
// Round 2: split distance work into k_argmin (token-major) and k_top5
// (code-major), both register-resident, 4 blocks/CU, conflict-free LDS.
// ---------------------------------------------------------------------------

// ---------------- Kernel 1: hp = normalize(h @ proj_w + b) -----------------
__global__ __launch_bounds__(256) void k_proj(
    const float* __restrict__ h, const float* __restrict__ w,
    const float* __restrict__ bias,
    float* __restrict__ hp_norm, float* __restrict__ h2) {
  __shared__ __align__(16) float hs[8 * 1024];
  __shared__ float red[256][9];
  __shared__ float hpv[8][64];
  const int tb = blockIdx.x * 8;
  const int tid = threadIdx.x;
  {
    const float4* h4 = (const float4*)(h + (size_t)tb * 1024);
    float4* hs4 = (float4*)hs;
#pragma unroll
    for (int i = 0; i < 8; ++i) hs4[tid + 256 * i] = h4[tid + 256 * i];
  }
  __syncthreads();
  const int dim = tid & 63;
  const int part = tid >> 6;
  float acc[8];
#pragma unroll
  for (int t = 0; t < 8; ++t) acc[t] = 0.f;
  for (int k = part; k < 1024; k += 4) {
    float wv = w[k * 64 + dim];
#pragma unroll
    for (int t = 0; t < 8; ++t) acc[t] = fmaf(hs[t * 1024 + k], wv, acc[t]);
  }
#pragma unroll
  for (int t = 0; t < 8; ++t) red[tid][t] = acc[t];
  __syncthreads();
#pragma unroll
  for (int i = 0; i < 2; ++i) {
    int idx = tid + i * 256;
    int t = idx >> 6, d = idx & 63;
    float s = red[d][t] + red[d + 64][t] + red[d + 128][t] + red[d + 192][t];
    hpv[t][d] = s + bias[d];
  }
  __syncthreads();
  const int wid = tid >> 6;
  const int lane = tid & 63;
#pragma unroll
  for (int t0 = 0; t0 < 2; ++t0) {
    int t = wid + t0 * 4;
    float v = hpv[t][lane];
    float sq = v * v;
#pragma unroll
    for (int o = 32; o > 0; o >>= 1) sq += __shfl_xor(sq, o, 64);
    float vn = v / sqrtf(sq);
    hp_norm[(size_t)(tb + t) * 64 + lane] = vn;
    float s2 = vn * vn;
#pragma unroll
    for (int o = 32; o > 0; o >>= 1) s2 += __shfl_xor(s2, o, 64);
    if (lane == 0) h2[tb + t] = s2;
  }
}

// ---------------- Kernel 2: E = normalize(emb), e2 = sum(E^2) --------------
__global__ __launch_bounds__(256) void k_enorm(
    const float* __restrict__ emb, float* __restrict__ E,
    float* __restrict__ e2) {
  const int c = blockIdx.x * 4 + (threadIdx.x >> 6);
  const int lane = threadIdx.x & 63;
  float v = emb[(size_t)c * 64 + lane];
  float sq = v * v;
#pragma unroll
  for (int o = 32; o > 0; o >>= 1) sq += __shfl_xor(sq, o, 64);
  float vn = v / sqrtf(sq);
  E[(size_t)c * 64 + lane] = vn;
  float s2 = vn * vn;
#pragma unroll
  for (int o = 32; o > 0; o >>= 1) s2 += __shfl_xor(s2, o, 64);
  if (lane == 0) e2[c] = s2;
}

// ---------------- Kernel 3a: argmin over codes (token-major) ---------------
// grid (128, 8): 64-token tile x 1024-code strip. 256 thr, thread = 4tok x 4code.
// tokg = tid&15 owns tokens {tokg+16i}; cg = tid>>4 owns codes {cg+16j}.
// Per-wave: threads sharing a token are lanes {l, l^16, l^32, l^48}.
__global__ __launch_bounds__(256, 4) void k_argmin(
    const float* __restrict__ hp, const float* __restrict__ h2g,
    const float* __restrict__ Eg, const float* __restrict__ e2g,
    const float* __restrict__ maskg,
    float* __restrict__ amin_d, int* __restrict__ amin_c) {
  __shared__ __align__(16) float hs[64 * 68];
  __shared__ __align__(16) float es[64 * 68];
  __shared__ float h2s[64], msks[64], e2s[64];
  const int tid = threadIdx.x;
  const int tb = blockIdx.x * 64;
  const int cbase = blockIdx.y * 1024;
  const int tokg = tid & 15;
  const int cg = tid >> 4;
  {
    const float4* hp4 = (const float4*)hp;
#pragma unroll
    for (int i = 0; i < 4; ++i) {
      int f4 = tid + 256 * i;
      int row = f4 >> 4, col = f4 & 15;
      *(float4*)&hs[row * 68 + col * 4] = hp4[(size_t)(tb + row) * 16 + col];
    }
    if (tid < 64) { h2s[tid] = h2g[tb + tid]; msks[tid] = maskg[tb + tid]; }
  }
  float bestd[4]; int bestc[4];
#pragma unroll
  for (int i = 0; i < 4; ++i) { bestd[i] = FLT_MAX; bestc[i] = 0x7fffffff; }
  for (int ch = 0; ch < 16; ++ch) {
    const int cs = cbase + ch * 64;
    __syncthreads();   // prev compute done; es safe to overwrite
    {
      const float4* E4 = (const float4*)Eg;
#pragma unroll
      for (int i = 0; i < 4; ++i) {
        int f4 = tid + 256 * i;
        int row = f4 >> 4, col = f4 & 15;
        *(float4*)&es[row * 68 + col * 4] = E4[(size_t)(cs + row) * 16 + col];
      }
      if (tid < 64) e2s[tid] = e2g[cs + tid];
    }
    __syncthreads();
    float acc[4][4];
#pragma unroll
    for (int i = 0; i < 4; ++i)
#pragma unroll
      for (int j = 0; j < 4; ++j) acc[i][j] = 0.f;
#pragma unroll 4
    for (int k4 = 0; k4 < 16; ++k4) {
      float4 av[4], bv[4];
#pragma unroll
      for (int i = 0; i < 4; ++i)
        av[i] = *(const float4*)&hs[(tokg + 16 * i) * 68 + k4 * 4];
#pragma unroll
      for (int j = 0; j < 4; ++j)
        bv[j] = *(const float4*)&es[(cg + 16 * j) * 68 + k4 * 4];
#pragma unroll
      for (int i = 0; i < 4; ++i)
#pragma unroll
        for (int j = 0; j < 4; ++j) {
          float s = acc[i][j];
          s = fmaf(av[i].x, bv[j].x, s);
          s = fmaf(av[i].y, bv[j].y, s);
          s = fmaf(av[i].z, bv[j].z, s);
          s = fmaf(av[i].w, bv[j].w, s);
          acc[i][j] = s;
        }
    }
#pragma unroll
    for (int i = 0; i < 4; ++i) {
      int tok = tokg + 16 * i;
      float h2v = h2s[tok], mt = msks[tok];
#pragma unroll
      for (int j = 0; j < 4; ++j) {   // codes ascending within thread
        int cl = cg + 16 * j;
        float dist = h2v + e2s[cl] - 2.f * acc[i][j];
        dist = dist * mt + 1.0e7f * (1.f - mt);
        int gc = cs + cl;
        if (dist < bestd[i]) { bestd[i] = dist; bestc[i] = gc; }
      }
    }
  }
  // in-wave reduce over the 4 code-groups sharing each token, then write
#pragma unroll
  for (int i = 0; i < 4; ++i) {
    float bd = bestd[i]; int bc = bestc[i];
    float od = __shfl_xor(bd, 16, 64); int oc = __shfl_xor(bc, 16, 64);
    if (od < bd || (od == bd && oc < bc)) { bd = od; bc = oc; }
    od = __shfl_xor(bd, 32, 64); oc = __shfl_xor(bc, 32, 64);
    if (od < bd || (od == bd && oc < bc)) { bd = od; bc = oc; }
    if ((tid & 48) == 0) {
      int t = tb + tokg + 16 * i;
      int w = tid >> 6;
      amin_d[(size_t)t * 32 + blockIdx.y * 4 + w] = bd;
      amin_c[(size_t)t * 32 + blockIdx.y * 4 + w] = bc;
    }
  }
}

// ---------------- Kernel 3b: top-5 tokens per code (code-major) ------------
// grid (128, 8): 64-code tile x 1024-token strip. codeg = tid&15 owns codes
// {codeg+16j}; tokg = tid>>4 owns tokens {tokg+16i} per chunk.
__global__ __launch_bounds__(256, 4) void k_top5(
    const float* __restrict__ hp, const float* __restrict__ h2g,
    const float* __restrict__ Eg, const float* __restrict__ e2g,
    const float* __restrict__ maskg,
    float* __restrict__ t5d, int* __restrict__ t5i) {
  __shared__ __align__(16) float hs[64 * 68];
  __shared__ __align__(16) float es[64 * 68];
  __shared__ float h2s[64], msks[64], e2f[64];
  const int tid = threadIdx.x;
  const int cb = blockIdx.x * 64;
  const int tbase = blockIdx.y * 1024;
  const int codeg = tid & 15;
  const int tokg = tid >> 4;
  {
    const float4* E4 = (const float4*)Eg;
#pragma unroll
    for (int i = 0; i < 4; ++i) {
      int f4 = tid + 256 * i;
      int row = f4 >> 4, col = f4 & 15;
      *(float4*)&es[row * 68 + col * 4] = E4[(size_t)(cb + row) * 16 + col];
    }
    if (tid < 64) e2f[tid] = e2g[cb + tid];
  }
  float td[4][5]; int ti_[4][5];
#pragma unroll
  for (int j = 0; j < 4; ++j)
#pragma unroll
    for (int s = 0; s < 5; ++s) { td[j][s] = FLT_MAX; ti_[j][s] = 0x7fffffff; }
  for (int ch = 0; ch < 16; ++ch) {
    const int ts = tbase + ch * 64;
    __syncthreads();
    {
      const float4* hp4 = (const float4*)hp;
#pragma unroll
      for (int i = 0; i < 4; ++i) {
        int f4 = tid + 256 * i;
        int row = f4 >> 4, col = f4 & 15;
        *(float4*)&hs[row * 68 + col * 4] = hp4[(size_t)(ts + row) * 16 + col];
      }
      if (tid < 64) { h2s[tid] = h2g[ts + tid]; msks[tid] = maskg[ts + tid]; }
    }
    __syncthreads();
    float acc[4][4];
#pragma unroll
    for (int i = 0; i < 4; ++i)
#pragma unroll
      for (int j = 0; j < 4; ++j) acc[i][j] = 0.f;
#pragma unroll 4
    for (int k4 = 0; k4 < 16; ++k4) {
      float4 av[4], bv[4];
#pragma unroll
      for (int i = 0; i < 4; ++i)
        av[i] = *(const float4*)&hs[(tokg + 16 * i) * 68 + k4 * 4];
#pragma unroll
      for (int j = 0; j < 4; ++j)
        bv[j] = *(const float4*)&es[(codeg + 16 * j) * 68 + k4 * 4];
#pragma unroll
      for (int i = 0; i < 4; ++i)
#pragma unroll
        for (int j = 0; j < 4; ++j) {
          float s = acc[i][j];
          s = fmaf(av[i].x, bv[j].x, s);
          s = fmaf(av[i].y, bv[j].y, s);
          s = fmaf(av[i].z, bv[j].z, s);
          s = fmaf(av[i].w, bv[j].w, s);
          acc[i][j] = s;
        }
    }
#pragma unroll
    for (int j = 0; j < 4; ++j) {
      float e2v = e2f[codeg + 16 * j];
#pragma unroll
      for (int i = 0; i < 4; ++i) {   // tokens ascending within thread
        int tok = tokg + 16 * i;
        float dist = h2s[tok] + e2v - 2.f * acc[i][j];
        float mt = msks[tok];
        dist = dist * mt + 1.0e7f * (1.f - mt);
        int tk = ts + tok;
        if (dist < td[j][4]) {
          td[j][4] = dist; ti_[j][4] = tk;
          if (td[j][4] < td[j][3]) { float x=td[j][3]; td[j][3]=td[j][4]; td[j][4]=x; int y=ti_[j][3]; ti_[j][3]=ti_[j][4]; ti_[j][4]=y; }
          if (td[j][3] < td[j][2]) { float x=td[j][2]; td[j][2]=td[j][3]; td[j][3]=x; int y=ti_[j][2]; ti_[j][2]=ti_[j][3]; ti_[j][3]=y; }
          if (td[j][2] < td[j][1]) { float x=td[j][1]; td[j][1]=td[j][2]; td[j][2]=x; int y=ti_[j][1]; ti_[j][1]=ti_[j][2]; ti_[j][2]=y; }
          if (td[j][1] < td[j][0]) { float x=td[j][0]; td[j][0]=td[j][1]; td[j][1]=x; int y=ti_[j][0]; ti_[j][0]=ti_[j][1]; ti_[j][1]=y; }
        }
      }
    }
  }
  // in-wave merge of the 4 token-group lists per code, write top-5 partial
  const int w = tid >> 6;
#pragma unroll
  for (int j = 0; j < 4; ++j) {
    bool chs[5] = {false, false, false, false, false};
#pragma unroll
    for (int r = 0; r < 5; ++r) {
      float bd = FLT_MAX; int bi = 0x7fffffff;
#pragma unroll
      for (int s = 0; s < 5; ++s) {
        bool better = !chs[s] && (td[j][s] < bd || (td[j][s] == bd && ti_[j][s] < bi));
        if (better) { bd = td[j][s]; bi = ti_[j][s]; }
      }
      float od = __shfl_xor(bd, 16, 64); int oi = __shfl_xor(bi, 16, 64);
      if (od < bd || (od == bd && oi < bi)) { bd = od; bi = oi; }
      od = __shfl_xor(bd, 32, 64); oi = __shfl_xor(bi, 32, 64);
      if (od < bd || (od == bd && oi < bi)) { bd = od; bi = oi; }
#pragma unroll
      for (int s = 0; s < 5; ++s) if (ti_[j][s] == bi) chs[s] = true;
      if ((tid & 48) == 0) {
        size_t base = ((size_t)(cb + codeg + 16 * j) * 32 + blockIdx.y * 4 + w) * 5 + r;
        t5d[base] = bd; t5i[base] = bi;
      }
    }
  }
}

// ---------------- init new_count = count -----------------------------------
__global__ void k_initcount(const float* __restrict__ cnt,
                            float* __restrict__ ncnt) {
  int i = blockIdx.x * 256 + threadIdx.x;
  ncnt[i] = cnt[i];
}

// ---------------- Kernel 4: merge argmin, code, histogram, token loss ------
__global__ __launch_bounds__(256) void k_code(
    const float* __restrict__ amin_d, const int* __restrict__ amin_c,
    const float* __restrict__ hp, const float* __restrict__ E,
    float* __restrict__ code_f, int* __restrict__ code_i,
    float* __restrict__ newcount, float* __restrict__ loss_tok) {
  const int wid = threadIdx.x >> 6;
  const int lane = threadIdx.x & 63;
  const int t = blockIdx.x * 4 + wid;
  float d = FLT_MAX;
  int c = 0x7fffffff;
  if (lane < 32) {
    d = amin_d[(size_t)t * 32 + lane];
    c = amin_c[(size_t)t * 32 + lane];
  }
#pragma unroll
  for (int o = 32; o > 0; o >>= 1) {
    float od = __shfl_xor(d, o, 64);
    int oc = __shfl_xor(c, o, 64);
    if (od < d || (od == d && oc < c)) { d = od; c = oc; }
  }
  c = __shfl(c, 0, 64);
  float a = hp[(size_t)t * 64 + lane];
  float e = E[(size_t)c * 64 + lane];
  float q = a + (e - a);
  float df = a - q;
  float ad = fabsf(df);
  float l = ad < 1.f ? 0.5f * df * df : ad - 0.5f;
#pragma unroll
  for (int o = 32; o > 0; o >>= 1) l += __shfl_xor(l, o, 64);
  if (lane == 0) {
    code_f[t] = (float)c;
    code_i[t] = c;
    loss_tok[t] = l;
    atomicAdd(&newcount[c], 1.0f);
  }
}

// ---------------- Kernel 5: q_out = q_ste @ proj_inv_w + b -----------------
__global__ __launch_bounds__(256) void k_qout(
    const int* __restrict__ code_i, const float* __restrict__ hp,
    const float* __restrict__ E, const float* __restrict__ w,
    const float* __restrict__ bias, float* __restrict__ qout) {
  __shared__ float qs[16][64];
  const int tid = threadIdx.x;
  const int tb = blockIdx.x * 16;
#pragma unroll
  for (int i = 0; i < 4; ++i) {
    int idx = tid + i * 256;
    int t = idx >> 6, j = idx & 63;
    int c = code_i[tb + t];
    float a = hp[(size_t)(tb + t) * 64 + j];
    float e = E[(size_t)c * 64 + j];
    qs[t][j] = a + (e - a);
  }
  __syncthreads();
  float acc[16][4];
#pragma unroll
  for (int t = 0; t < 16; ++t)
#pragma unroll
    for (int j = 0; j < 4; ++j) acc[t][j] = 0.f;
  const float4* w4 = (const float4*)w;
  for (int k = 0; k < 64; ++k) {
    float4 wv = w4[k * 256 + tid];
#pragma unroll
    for (int t = 0; t < 16; ++t) {
      float q = qs[t][k];
      acc[t][0] = fmaf(q, wv.x, acc[t][0]);
      acc[t][1] = fmaf(q, wv.y, acc[t][1]);
      acc[t][2] = fmaf(q, wv.z, acc[t][2]);
      acc[t][3] = fmaf(q, wv.w, acc[t][3]);
    }
  }
  const float4 bv = ((const float4*)bias)[tid];
  float4* o4 = (float4*)qout;
#pragma unroll
  for (int t = 0; t < 16; ++t) {
    float4 r;
    r.x = acc[t][0] + bv.x; r.y = acc[t][1] + bv.y;
    r.z = acc[t][2] + bv.z; r.w = acc[t][3] + bv.w;
    o4[(size_t)(tb + t) * 256 + tid] = r;
  }
}

// ---------------- Kernel 6: merge 32 top5 partials, EMA update -------------
// One wave per code; lanes 0..31 hold the 32 partial sorted-5 lists.
__global__ __launch_bounds__(256) void k_emb(
    const float* __restrict__ t5d, const int* __restrict__ t5i,
    const float* __restrict__ hp, const float* __restrict__ E,
    float* __restrict__ newemb) {
  const int wid = threadIdx.x >> 6;
  const int lane = threadIdx.x & 63;
  const int c = blockIdx.x * 4 + wid;
  float cd[5]; int ci[5];
  if (lane < 32) {
    size_t base = ((size_t)c * 32 + lane) * 5;
#pragma unroll
    for (int s = 0; s < 5; ++s) { cd[s] = t5d[base + s]; ci[s] = t5i[base + s]; }
  } else {
#pragma unroll
    for (int s = 0; s < 5; ++s) { cd[s] = FLT_MAX; ci[s] = 0x7fffffff; }
  }
  bool chosen[5] = {false, false, false, false, false};
  int sel[5]; float seld[5];
#pragma unroll
  for (int r = 0; r < 5; ++r) {
    float bd = FLT_MAX; int bi = 0x7fffffff;
#pragma unroll
    for (int s = 0; s < 5; ++s) {
      bool better = !chosen[s] && (cd[s] < bd || (cd[s] == bd && ci[s] < bi));
      if (better) { bd = cd[s]; bi = ci[s]; }
    }
#pragma unroll
    for (int o = 32; o > 0; o >>= 1) {
      float od = __shfl_xor(bd, o, 64);
      int oi = __shfl_xor(bi, o, 64);
      if (od < bd || (od == bd && oi < bi)) { bd = od; bi = oi; }
    }
    sel[r] = bi; seld[r] = bd;
#pragma unroll
    for (int s = 0; s < 5; ++s) if (ci[s] == bi) chosen[s] = true;
  }
  float m5 = fabsf(seld[0]);
#pragma unroll
  for (int r = 1; r < 5; ++r) m5 = fminf(m5, fabsf(seld[r]));
  float hf = 0.f;
#pragma unroll
  for (int r = 0; r < 5; ++r) hf += hp[(size_t)sel[r] * 64 + lane];
  hf = hf / 5.0f;
  float ev = E[(size_t)c * 64 + lane];
  float outv = (m5 > 0.1f) ? (ev * 0.995f + hf * (float)(1.0 - 0.995)) : ev;
  newemb[(size_t)c * 64 + lane] = outv;
}

// ---------------- Kernel 7: vq_loss ----------------------------------------
__global__ __launch_bounds__(256) void k_vq(
    const float* __restrict__ loss_tok, const float* __restrict__ maskg,
    float* __restrict__ vq) {
  __shared__ float S[256], M[256];
  const int tid = threadIdx.x;
  float s = 0.f, m = 0.f;
  const int base = tid * 32;
  for (int i = 0; i < 32; ++i) {
    float mm = maskg[base + i];
    s = fmaf(loss_tok[base + i], mm, s);
    m += mm;
  }
  S[tid] = s; M[tid] = m;
  __syncthreads();
  if (tid == 0) {
    float tot = 0.f;
    for (int b = 0; b < 4; ++b) {
      float sb = 0.f, mb = 0.f;
      for (int i = 0; i < 64; ++i) { sb += S[b * 64 + i]; mb += M[b * 64 + i]; }
      tot += sb / mb;
    }
    vq[0] = tot * 1.25f / 256.0f;
  }
}

// ---------------------------------------------------------------------------
extern "C" void kernel_launch(void* const* d_in, const int* in_sizes, int n_in,
                              void* d_out, int out_size, void* d_ws,
                              size_t ws_size, hipStream_t stream) {
  (void)in_sizes; (void)n_in; (void)out_size; (void)ws_size;
  const float* h          = (const float*)d_in[0];
  const float* mask       = (const float*)d_in[1];
  const float* proj_w     = (const float*)d_in[2];
  const float* proj_b     = (const float*)d_in[3];
  const float* proj_inv_w = (const float*)d_in[4];
  const float* proj_inv_b = (const float*)d_in[5];
  const float* emb        = (const float*)d_in[6];
  const float* count      = (const float*)d_in[7];

  float* out      = (float*)d_out;
  float* q_out    = out;                 // 8388608
  float* code_f   = out + 8388608;       // 8192
  float* vq       = out + 8396800;       // 1
  float* newemb   = out + 8396801;       // 524288
  float* newcount = out + 8921089;       // 8192

  float* ws       = (float*)d_ws;
  float* hp_norm  = ws;                       // 524288
  float* h2       = ws + 524288;              // 8192
  float* E        = ws + 532480;              // 524288
  float* e2       = ws + 1056768;             // 8192
  float* amin_d   = ws + 1064960;             // 262144 (8192*32)
  int*   amin_c   = (int*)(ws + 1327104);     // 262144
  int*   code_i   = (int*)(ws + 1589248);     // 8192
  float* t5d      = ws + 1597440;             // 1310720 (8192*32*5)
  int*   t5i      = (int*)(ws + 2908160);     // 1310720
  float* loss_tok = ws + 4218880;             // 8192  (total ~16.9 MB)

  k_proj<<<1024, 256, 0, stream>>>(h, proj_w, proj_b, hp_norm, h2);
  k_enorm<<<2048, 256, 0, stream>>>(emb, E, e2);
  k_argmin<<<dim3(128, 8), 256, 0, stream>>>(hp_norm, h2, E, e2, mask,
                                             amin_d, amin_c);
  k_top5<<<dim3(128, 8), 256, 0, stream>>>(hp_norm, h2, E, e2, mask,
                                           t5d, t5i);
  k_initcount<<<32, 256, 0, stream>>>(count, newcount);
  k_code<<<2048, 256, 0, stream>>>(amin_d, amin_c, hp_norm, E,
                                   code_f, code_i, newcount, loss_tok);
  k_qout<<<512, 256, 0, stream>>>(code_i, hp_norm, E, proj_inv_w, proj_inv_b,
                                  q_out);
  k_emb<<<2048, 256, 0, stream>>>(t5d, t5i, hp_norm, E, newemb);
  k_vq<<<1, 256, 0, stream>>>(loss_tok, mask, vq);
}

// Round 3
// 303.133 us; speedup vs baseline: 3.0507x; 1.6346x over previous
//
#include <hip/hip_runtime.h>
#include <float.h>

// ---------------------------------------------------------------------------
// VQ layer forward, MI355X. B=4, L=2048 (8192 tokens), D=1024, VQ_DIM=64,
// K_CODES=8192, EMA_K=5.
// Round 3: distance GEMM on matrix cores via bf16 hi/lo split (4-term MFMA,
// f32 accumulate). k_argmin: tokens register-resident, codes stream.
// k_top5: codes register-resident, tokens stream. No LDS staging, no barriers
// in the main loops. Coalesced partial outputs (round-2 had 16x write
// amplification: WRITE_SIZE 164MB for 10.5MB of data).
// ---------------------------------------------------------------------------

typedef __attribute__((ext_vector_type(8)))  short bf16x8;   // 8 bf16 = 4 VGPR
typedef __attribute__((ext_vector_type(16))) float f32x16;   // MFMA 32x32 acc

__device__ __forceinline__ unsigned short f2bf(float x) {
  unsigned u = __float_as_uint(x);
  unsigned r = (u + 0x7fffu + ((u >> 16) & 1u)) >> 16;   // RNE
  return (unsigned short)r;
}
__device__ __forceinline__ float bf2f(unsigned short b) {
  return __uint_as_float(((unsigned)b) << 16);
}

// sorted-5 insert, plain strict < (ties keep existing = earlier/lower index)
__device__ __forceinline__ void tins5(float& d0, float& d1, float& d2,
                                      float& d3, float& d4, int& i0, int& i1,
                                      int& i2, int& i3, int& i4, float dv,
                                      int iv) {
  if (dv < d4) {
    d4 = dv; i4 = iv;
    if (d4 < d3) { float t = d3; d3 = d4; d4 = t; int u = i3; i3 = i4; i4 = u; }
    if (d3 < d2) { float t = d2; d2 = d3; d3 = t; int u = i2; i2 = i3; i3 = u; }
    if (d2 < d1) { float t = d1; d1 = d2; d2 = t; int u = i1; i1 = i2; i2 = u; }
    if (d1 < d0) { float t = d0; d0 = d1; d1 = t; int u = i0; i0 = i1; i1 = u; }
  }
}
// sorted-5 insert, lexicographic (d, idx) — for cross-lane/wave merges
__device__ __forceinline__ void lins5(float& d0, float& d1, float& d2,
                                      float& d3, float& d4, int& i0, int& i1,
                                      int& i2, int& i3, int& i4, float dv,
                                      int iv) {
  if (dv < d4 || (dv == d4 && iv < i4)) {
    d4 = dv; i4 = iv;
    if (d4 < d3 || (d4 == d3 && i4 < i3)) { float t = d3; d3 = d4; d4 = t; int u = i3; i3 = i4; i4 = u; }
    if (d3 < d2 || (d3 == d2 && i3 < i2)) { float t = d2; d2 = d3; d3 = t; int u = i2; i2 = i3; i3 = u; }
    if (d2 < d1 || (d2 == d1 && i2 < i1)) { float t = d1; d1 = d2; d2 = t; int u = i1; i1 = i2; i2 = u; }
    if (d1 < d0 || (d1 == d0 && i1 < i0)) { float t = d0; d0 = d1; d1 = t; int u = i0; i0 = i1; i1 = u; }
  }
}

// ---------------- Kernel 1: hp = normalize(h @ proj_w + b), + bf16 split ---
__global__ __launch_bounds__(256) void k_proj(
    const float* __restrict__ h, const float* __restrict__ w,
    const float* __restrict__ bias, float* __restrict__ hp_norm,
    float* __restrict__ h2, unsigned short* __restrict__ hpH,
    unsigned short* __restrict__ hpL) {
  __shared__ __align__(16) float hs[8 * 1024];
  __shared__ float red[256][9];
  __shared__ float hpv[8][64];
  const int tb = blockIdx.x * 8;
  const int tid = threadIdx.x;
  {
    const float4* h4 = (const float4*)(h + (size_t)tb * 1024);
    float4* hs4 = (float4*)hs;
#pragma unroll
    for (int i = 0; i < 8; ++i) hs4[tid + 256 * i] = h4[tid + 256 * i];
  }
  __syncthreads();
  const int dim = tid & 63;
  const int part = tid >> 6;
  float acc[8];
#pragma unroll
  for (int t = 0; t < 8; ++t) acc[t] = 0.f;
  for (int k = part; k < 1024; k += 4) {
    float wv = w[k * 64 + dim];
#pragma unroll
    for (int t = 0; t < 8; ++t) acc[t] = fmaf(hs[t * 1024 + k], wv, acc[t]);
  }
#pragma unroll
  for (int t = 0; t < 8; ++t) red[tid][t] = acc[t];
  __syncthreads();
#pragma unroll
  for (int i = 0; i < 2; ++i) {
    int idx = tid + i * 256;
    int t = idx >> 6, d = idx & 63;
    float s = red[d][t] + red[d + 64][t] + red[d + 128][t] + red[d + 192][t];
    hpv[t][d] = s + bias[d];
  }
  __syncthreads();
  const int wid = tid >> 6;
  const int lane = tid & 63;
#pragma unroll
  for (int t0 = 0; t0 < 2; ++t0) {
    int t = wid + t0 * 4;
    float v = hpv[t][lane];
    float sq = v * v;
#pragma unroll
    for (int o = 32; o > 0; o >>= 1) sq += __shfl_xor(sq, o, 64);
    float vn = v / sqrtf(sq);
    size_t oidx = (size_t)(tb + t) * 64 + lane;
    hp_norm[oidx] = vn;
    unsigned short hb = f2bf(vn);
    hpH[oidx] = hb;
    hpL[oidx] = f2bf(vn - bf2f(hb));
    float s2 = vn * vn;
#pragma unroll
    for (int o = 32; o > 0; o >>= 1) s2 += __shfl_xor(s2, o, 64);
    if (lane == 0) h2[tb + t] = s2;
  }
}

// ---------------- Kernel 2: E = normalize(emb), e2, + bf16 split -----------
__global__ __launch_bounds__(256) void k_enorm(
    const float* __restrict__ emb, float* __restrict__ E,
    float* __restrict__ e2, unsigned short* __restrict__ EH,
    unsigned short* __restrict__ EL) {
  const int c = blockIdx.x * 4 + (threadIdx.x >> 6);
  const int lane = threadIdx.x & 63;
  float v = emb[(size_t)c * 64 + lane];
  float sq = v * v;
#pragma unroll
  for (int o = 32; o > 0; o >>= 1) sq += __shfl_xor(sq, o, 64);
  float vn = v / sqrtf(sq);
  size_t oidx = (size_t)c * 64 + lane;
  E[oidx] = vn;
  unsigned short hb = f2bf(vn);
  EH[oidx] = hb;
  EL[oidx] = f2bf(vn - bf2f(hb));
  float s2 = vn * vn;
#pragma unroll
  for (int o = 32; o > 0; o >>= 1) s2 += __shfl_xor(s2, o, 64);
  if (lane == 0) e2[c] = s2;
}

// ---------------- Kernel 3a: argmin over codes (MFMA) ----------------------
// grid (128 token-tiles, 4 code-strips). Block: 64 tokens resident in A-frags,
// streams 2048 codes in 32 chunks of 64. Wave w: rowg=w>>1 (token half),
// colg=w&1 (code half). MFMA 32x32x16 bf16: C col=lane&31,
// row=(reg&3)+8*(reg>>2)+4*(lane>>5). A: row=lane&31, k=(lane>>5)*8+i. B: dual.
__global__ __launch_bounds__(256, 2) void k_argmin(
    const unsigned short* __restrict__ hpH, const unsigned short* __restrict__ hpL,
    const unsigned short* __restrict__ EH, const unsigned short* __restrict__ EL,
    const float* __restrict__ h2g, const float* __restrict__ e2g,
    float* __restrict__ amin_d, int* __restrict__ amin_c) {
  __shared__ float mD[2][64];
  __shared__ int mC[2][64];
  const int tid = threadIdx.x;
  const int w = tid >> 6, lane = tid & 63;
  const int l31 = lane & 31, lh = lane >> 5;
  const int rowg = w >> 1, colg = w & 1;
  const int tok_base = blockIdx.x * 64;
  const int row_t = tok_base + rowg * 32 + l31;
  bf16x8 aH[4], aL[4];
#pragma unroll
  for (int ks = 0; ks < 4; ++ks) {
    aH[ks] = *(const bf16x8*)(hpH + (size_t)row_t * 64 + ks * 16 + lh * 8);
    aL[ks] = *(const bf16x8*)(hpL + (size_t)row_t * 64 + ks * 16 + lh * 8);
  }
  float h2r[16];
#pragma unroll
  for (int r = 0; r < 16; ++r) {
    int roff = (r & 3) + 8 * (r >> 2) + 4 * lh;
    h2r[r] = h2g[tok_base + rowg * 32 + roff];
  }
  float bd[16]; int bc[16];
#pragma unroll
  for (int r = 0; r < 16; ++r) { bd[r] = FLT_MAX; bc[r] = 0x7fffffff; }
  const int cstrip = blockIdx.y * 2048;
#pragma unroll 2
  for (int ch = 0; ch < 32; ++ch) {
    const int col_c = cstrip + ch * 64 + colg * 32 + l31;
    bf16x8 bH[4], bL[4];
#pragma unroll
    for (int ks = 0; ks < 4; ++ks) {
      bH[ks] = *(const bf16x8*)(EH + (size_t)col_c * 64 + ks * 16 + lh * 8);
      bL[ks] = *(const bf16x8*)(EL + (size_t)col_c * 64 + ks * 16 + lh * 8);
    }
    float e2c = e2g[col_c];
    f32x16 acc = {};
#pragma unroll
    for (int ks = 0; ks < 4; ++ks)
      acc = __builtin_amdgcn_mfma_f32_32x32x16_bf16(aL[ks], bL[ks], acc, 0, 0, 0);
#pragma unroll
    for (int ks = 0; ks < 4; ++ks)
      acc = __builtin_amdgcn_mfma_f32_32x32x16_bf16(aL[ks], bH[ks], acc, 0, 0, 0);
#pragma unroll
    for (int ks = 0; ks < 4; ++ks)
      acc = __builtin_amdgcn_mfma_f32_32x32x16_bf16(aH[ks], bL[ks], acc, 0, 0, 0);
#pragma unroll
    for (int ks = 0; ks < 4; ++ks)
      acc = __builtin_amdgcn_mfma_f32_32x32x16_bf16(aH[ks], bH[ks], acc, 0, 0, 0);
#pragma unroll
    for (int r = 0; r < 16; ++r) {
      float s = h2r[r] + e2c;               // ref order: (h2+e2) - 2*dot
      float d = fmaf(-2.f, acc[r], s);
      if (d < bd[r]) { bd[r] = d; bc[r] = col_c; }  // codes ascend: strict <
    }
  }
  // reduce over the 32 lanes of each half (same 16 rows, 32 different codes)
#pragma unroll
  for (int r = 0; r < 16; ++r) {
#pragma unroll
    for (int o = 1; o <= 16; o <<= 1) {
      float od = __shfl_xor(bd[r], o, 64);
      int oc = __shfl_xor(bc[r], o, 64);
      if (od < bd[r] || (od == bd[r] && oc < bc[r])) { bd[r] = od; bc[r] = oc; }
    }
  }
  if (l31 == 0) {   // lanes 0 and 32 hold the per-half winners
#pragma unroll
    for (int r = 0; r < 16; ++r) {
      int roff = (r & 3) + 8 * (r >> 2) + 4 * lh;
      mD[colg][rowg * 32 + roff] = bd[r];
      mC[colg][rowg * 32 + roff] = bc[r];
    }
  }
  __syncthreads();
  if (tid < 64) {
    float d0 = mD[0][tid], d1 = mD[1][tid];
    int c0 = mC[0][tid], c1 = mC[1][tid];
    if (d1 < d0 || (d1 == d0 && c1 < c0)) { d0 = d1; c0 = c1; }
    int t = tok_base + tid;
    amin_d[(size_t)t * 4 + blockIdx.y] = d0;
    amin_c[(size_t)t * 4 + blockIdx.y] = c0;
  }
}

// ---------------- Kernel 3b: top-5 tokens per code (MFMA) ------------------
// grid (128 code-tiles, 4 token-strips). Block: 64 codes resident in B-frags,
// streams 2048 tokens in 32 chunks of 64. Per-lane running sorted-5 for its
// fixed code column; lexicographic merges at the end.
__global__ __launch_bounds__(256, 2) void k_top5(
    const unsigned short* __restrict__ hpH, const unsigned short* __restrict__ hpL,
    const unsigned short* __restrict__ EH, const unsigned short* __restrict__ EL,
    const float* __restrict__ h2g, const float* __restrict__ e2g,
    const float* __restrict__ maskg,
    float* __restrict__ t5d, int* __restrict__ t5i) {
  __shared__ float At[2048], Bm[2048], C1[2048];
  __shared__ float sD[2][2][32][5];
  __shared__ int sI[2][2][32][5];
  const int tid = threadIdx.x;
  const int w = tid >> 6, lane = tid & 63;
  const int l31 = lane & 31, lh = lane >> 5;
  const int rowg = w >> 1, colg = w & 1;
  const int code_base = blockIdx.x * 64;
  const int col_c = code_base + colg * 32 + l31;
  const int tstrip = blockIdx.y * 2048;
#pragma unroll
  for (int i = 0; i < 8; ++i) {
    int t = tid + i * 256;
    float m = maskg[tstrip + t];
    At[t] = h2g[tstrip + t];
    Bm[t] = m;
    C1[t] = 1.0e7f * (1.f - m);
  }
  bf16x8 bH[4], bL[4];
#pragma unroll
  for (int ks = 0; ks < 4; ++ks) {
    bH[ks] = *(const bf16x8*)(EH + (size_t)col_c * 64 + ks * 16 + lh * 8);
    bL[ks] = *(const bf16x8*)(EL + (size_t)col_c * 64 + ks * 16 + lh * 8);
  }
  const float e2c = e2g[col_c];
  float td0 = FLT_MAX, td1 = FLT_MAX, td2 = FLT_MAX, td3 = FLT_MAX, td4 = FLT_MAX;
  int ti0 = 0x7fffffff, ti1 = 0x7fffffff, ti2 = 0x7fffffff, ti3 = 0x7fffffff,
      ti4 = 0x7fffffff;
  __syncthreads();
#pragma unroll 2
  for (int ch = 0; ch < 32; ++ch) {
    const int rowbase = ch * 64 + rowg * 32 + 4 * lh;   // strip-local
    const int row_t = tstrip + ch * 64 + rowg * 32 + l31;
    bf16x8 aH[4], aL[4];
#pragma unroll
    for (int ks = 0; ks < 4; ++ks) {
      aH[ks] = *(const bf16x8*)(hpH + (size_t)row_t * 64 + ks * 16 + lh * 8);
      aL[ks] = *(const bf16x8*)(hpL + (size_t)row_t * 64 + ks * 16 + lh * 8);
    }
    f32x16 acc = {};
#pragma unroll
    for (int ks = 0; ks < 4; ++ks)
      acc = __builtin_amdgcn_mfma_f32_32x32x16_bf16(aL[ks], bL[ks], acc, 0, 0, 0);
#pragma unroll
    for (int ks = 0; ks < 4; ++ks)
      acc = __builtin_amdgcn_mfma_f32_32x32x16_bf16(aL[ks], bH[ks], acc, 0, 0, 0);
#pragma unroll
    for (int ks = 0; ks < 4; ++ks)
      acc = __builtin_amdgcn_mfma_f32_32x32x16_bf16(aH[ks], bL[ks], acc, 0, 0, 0);
#pragma unroll
    for (int ks = 0; ks < 4; ++ks)
      acc = __builtin_amdgcn_mfma_f32_32x32x16_bf16(aH[ks], bH[ks], acc, 0, 0, 0);
    const int tok0 = tstrip + rowbase;
#pragma unroll
    for (int rq = 0; rq < 4; ++rq) {
      float2 a01 = *(const float2*)&At[rowbase + 8 * rq];
      float2 a23 = *(const float2*)&At[rowbase + 8 * rq + 2];
      float2 m01 = *(const float2*)&Bm[rowbase + 8 * rq];
      float2 m23 = *(const float2*)&Bm[rowbase + 8 * rq + 2];
      float2 c01 = *(const float2*)&C1[rowbase + 8 * rq];
      float2 c23 = *(const float2*)&C1[rowbase + 8 * rq + 2];
      float s, d;
      s = a01.x + e2c; d = fmaf(-2.f, acc[4 * rq + 0], s); d = fmaf(d, m01.x, c01.x);
      tins5(td0, td1, td2, td3, td4, ti0, ti1, ti2, ti3, ti4, d, tok0 + 8 * rq + 0);
      s = a01.y + e2c; d = fmaf(-2.f, acc[4 * rq + 1], s); d = fmaf(d, m01.y, c01.y);
      tins5(td0, td1, td2, td3, td4, ti0, ti1, ti2, ti3, ti4, d, tok0 + 8 * rq + 1);
      s = a23.x + e2c; d = fmaf(-2.f, acc[4 * rq + 2], s); d = fmaf(d, m23.x, c23.x);
      tins5(td0, td1, td2, td3, td4, ti0, ti1, ti2, ti3, ti4, d, tok0 + 8 * rq + 2);
      s = a23.y + e2c; d = fmaf(-2.f, acc[4 * rq + 3], s); d = fmaf(d, m23.y, c23.y);
      tins5(td0, td1, td2, td3, td4, ti0, ti1, ti2, ti3, ti4, d, tok0 + 8 * rq + 3);
    }
  }
  // merge lane <-> lane^32 (same code column, other row-half). Snapshot first.
  {
    float od0 = __shfl_xor(td0, 32, 64), od1 = __shfl_xor(td1, 32, 64),
          od2 = __shfl_xor(td2, 32, 64), od3 = __shfl_xor(td3, 32, 64),
          od4 = __shfl_xor(td4, 32, 64);
    int oi0 = __shfl_xor(ti0, 32, 64), oi1 = __shfl_xor(ti1, 32, 64),
        oi2 = __shfl_xor(ti2, 32, 64), oi3 = __shfl_xor(ti3, 32, 64),
        oi4 = __shfl_xor(ti4, 32, 64);
    lins5(td0, td1, td2, td3, td4, ti0, ti1, ti2, ti3, ti4, od0, oi0);
    lins5(td0, td1, td2, td3, td4, ti0, ti1, ti2, ti3, ti4, od1, oi1);
    lins5(td0, td1, td2, td3, td4, ti0, ti1, ti2, ti3, ti4, od2, oi2);
    lins5(td0, td1, td2, td3, td4, ti0, ti1, ti2, ti3, ti4, od3, oi3);
    lins5(td0, td1, td2, td3, td4, ti0, ti1, ti2, ti3, ti4, od4, oi4);
  }
  if (lane < 32) {
    sD[colg][rowg][l31][0] = td0; sD[colg][rowg][l31][1] = td1;
    sD[colg][rowg][l31][2] = td2; sD[colg][rowg][l31][3] = td3;
    sD[colg][rowg][l31][4] = td4;
    sI[colg][rowg][l31][0] = ti0; sI[colg][rowg][l31][1] = ti1;
    sI[colg][rowg][l31][2] = ti2; sI[colg][rowg][l31][3] = ti3;
    sI[colg][rowg][l31][4] = ti4;
  }
  __syncthreads();
  if (tid < 64) {
    int cg = tid >> 5, cl = tid & 31;
    float rd0 = sD[cg][0][cl][0], rd1 = sD[cg][0][cl][1], rd2 = sD[cg][0][cl][2],
          rd3 = sD[cg][0][cl][3], rd4 = sD[cg][0][cl][4];
    int ri0 = sI[cg][0][cl][0], ri1 = sI[cg][0][cl][1], ri2 = sI[cg][0][cl][2],
        ri3 = sI[cg][0][cl][3], ri4 = sI[cg][0][cl][4];
#pragma unroll
    for (int s = 0; s < 5; ++s) {
      lins5(rd0, rd1, rd2, rd3, rd4, ri0, ri1, ri2, ri3, ri4,
            sD[cg][1][cl][s], sI[cg][1][cl][s]);
    }
    int code = code_base + cg * 32 + cl;
    size_t gb = (size_t)code * 20 + (size_t)blockIdx.y * 5;
    t5d[gb + 0] = rd0; t5i[gb + 0] = ri0;
    t5d[gb + 1] = rd1; t5i[gb + 1] = ri1;
    t5d[gb + 2] = rd2; t5i[gb + 2] = ri2;
    t5d[gb + 3] = rd3; t5i[gb + 3] = ri3;
    t5d[gb + 4] = rd4; t5i[gb + 4] = ri4;
  }
}

// ---------------- init new_count = count -----------------------------------
__global__ void k_initcount(const float* __restrict__ cnt,
                            float* __restrict__ ncnt) {
  int i = blockIdx.x * 256 + threadIdx.x;
  ncnt[i] = cnt[i];
}

// ---------------- Kernel 4: merge argmin, code, histogram, token loss ------
__global__ __launch_bounds__(256) void k_code(
    const float* __restrict__ amin_d, const int* __restrict__ amin_c,
    const float* __restrict__ hp, const float* __restrict__ E,
    const float* __restrict__ maskg,
    float* __restrict__ code_f, int* __restrict__ code_i,
    float* __restrict__ newcount, float* __restrict__ loss_tok) {
  const int wid = threadIdx.x >> 6;
  const int lane = threadIdx.x & 63;
  const int t = blockIdx.x * 4 + wid;
  float d = FLT_MAX;
  int c = 0x7fffffff;
  if (lane < 4) {
    d = amin_d[(size_t)t * 4 + lane];
    c = amin_c[(size_t)t * 4 + lane];
  }
#pragma unroll
  for (int o = 1; o <= 2; o <<= 1) {
    float od = __shfl_xor(d, o, 64);
    int oc = __shfl_xor(c, o, 64);
    if (od < d || (od == d && oc < c)) { d = od; c = oc; }
  }
  c = __shfl(c, 0, 64);
  if (maskg[t] == 0.f) c = 0;   // masked row: all dists 1e7 -> argmin = 0
  float a = hp[(size_t)t * 64 + lane];
  float e = E[(size_t)c * 64 + lane];
  float q = a + (e - a);
  float df = a - q;
  float ad = fabsf(df);
  float l = ad < 1.f ? 0.5f * df * df : ad - 0.5f;
#pragma unroll
  for (int o = 32; o > 0; o >>= 1) l += __shfl_xor(l, o, 64);
  if (lane == 0) {
    code_f[t] = (float)c;
    code_i[t] = c;
    loss_tok[t] = l;
    atomicAdd(&newcount[c], 1.0f);
  }
}

// ---------------- Kernel 5: q_out = q_ste @ proj_inv_w + b -----------------
__global__ __launch_bounds__(256) void k_qout(
    const int* __restrict__ code_i, const float* __restrict__ hp,
    const float* __restrict__ E, const float* __restrict__ w,
    const float* __restrict__ bias, float* __restrict__ qout) {
  __shared__ float qs[16][64];
  const int tid = threadIdx.x;
  const int tb = blockIdx.x * 16;
#pragma unroll
  for (int i = 0; i < 4; ++i) {
    int idx = tid + i * 256;
    int t = idx >> 6, j = idx & 63;
    int c = code_i[tb + t];
    float a = hp[(size_t)(tb + t) * 64 + j];
    float e = E[(size_t)c * 64 + j];
    qs[t][j] = a + (e - a);
  }
  __syncthreads();
  float acc[16][4];
#pragma unroll
  for (int t = 0; t < 16; ++t)
#pragma unroll
    for (int j = 0; j < 4; ++j) acc[t][j] = 0.f;
  const float4* w4 = (const float4*)w;
  for (int k = 0; k < 64; ++k) {
    float4 wv = w4[k * 256 + tid];
#pragma unroll
    for (int t = 0; t < 16; ++t) {
      float q = qs[t][k];
      acc[t][0] = fmaf(q, wv.x, acc[t][0]);
      acc[t][1] = fmaf(q, wv.y, acc[t][1]);
      acc[t][2] = fmaf(q, wv.z, acc[t][2]);
      acc[t][3] = fmaf(q, wv.w, acc[t][3]);
    }
  }
  const float4 bv = ((const float4*)bias)[tid];
  float4* o4 = (float4*)qout;
#pragma unroll
  for (int t = 0; t < 16; ++t) {
    float4 r;
    r.x = acc[t][0] + bv.x; r.y = acc[t][1] + bv.y;
    r.z = acc[t][2] + bv.z; r.w = acc[t][3] + bv.w;
    o4[(size_t)(tb + t) * 256 + tid] = r;
  }
}

// ---------------- Kernel 6: merge 4 strip top5 lists, EMA update -----------
__global__ __launch_bounds__(256) void k_emb(
    const float* __restrict__ t5d, const int* __restrict__ t5i,
    const float* __restrict__ hp, const float* __restrict__ E,
    float* __restrict__ newemb) {
  const int wid = threadIdx.x >> 6;
  const int lane = threadIdx.x & 63;
  const int c = blockIdx.x * 4 + wid;
  float d = FLT_MAX;
  int idx = 0x7fffffff;
  if (lane < 20) {
    d = t5d[(size_t)c * 20 + lane];
    idx = t5i[(size_t)c * 20 + lane];
  }
  float seld[5]; int sel[5];
#pragma unroll
  for (int r = 0; r < 5; ++r) {
    float bd = d; int bi = idx;
#pragma unroll
    for (int o = 1; o <= 32; o <<= 1) {
      float od = __shfl_xor(bd, o, 64);
      int oi = __shfl_xor(bi, o, 64);
      if (od < bd || (od == bd && oi < bi)) { bd = od; bi = oi; }
    }
    seld[r] = bd; sel[r] = bi;
    if (idx == bi) d = FLT_MAX;   // token ids unique across strips
  }
  float m5 = fabsf(seld[0]);
#pragma unroll
  for (int r = 1; r < 5; ++r) m5 = fminf(m5, fabsf(seld[r]));
  float hf = 0.f;
#pragma unroll
  for (int r = 0; r < 5; ++r) hf += hp[(size_t)sel[r] * 64 + lane];
  hf = hf / 5.0f;
  float ev = E[(size_t)c * 64 + lane];
  float outv = (m5 > 0.1f) ? (ev * 0.995f + hf * (float)(1.0 - 0.995)) : ev;
  newemb[(size_t)c * 64 + lane] = outv;
}

// ---------------- Kernel 7: vq_loss ----------------------------------------
__global__ __launch_bounds__(256) void k_vq(
    const float* __restrict__ loss_tok, const float* __restrict__ maskg,
    float* __restrict__ vq) {
  __shared__ float S[256], M[256];
  const int tid = threadIdx.x;
  float s = 0.f, m = 0.f;
  const int base = tid * 32;
  for (int i = 0; i < 32; ++i) {
    float mm = maskg[base + i];
    s = fmaf(loss_tok[base + i], mm, s);
    m += mm;
  }
  S[tid] = s; M[tid] = m;
  __syncthreads();
  if (tid == 0) {
    float tot = 0.f;
    for (int b = 0; b < 4; ++b) {
      float sb = 0.f, mb = 0.f;
      for (int i = 0; i < 64; ++i) { sb += S[b * 64 + i]; mb += M[b * 64 + i]; }
      tot += sb / mb;
    }
    vq[0] = tot * 1.25f / 256.0f;
  }
}

// ---------------------------------------------------------------------------
extern "C" void kernel_launch(void* const* d_in, const int* in_sizes, int n_in,
                              void* d_out, int out_size, void* d_ws,
                              size_t ws_size, hipStream_t stream) {
  (void)in_sizes; (void)n_in; (void)out_size; (void)ws_size;
  const float* h          = (const float*)d_in[0];
  const float* mask       = (const float*)d_in[1];
  const float* proj_w     = (const float*)d_in[2];
  const float* proj_b     = (const float*)d_in[3];
  const float* proj_inv_w = (const float*)d_in[4];
  const float* proj_inv_b = (const float*)d_in[5];
  const float* emb        = (const float*)d_in[6];
  const float* count      = (const float*)d_in[7];

  float* out      = (float*)d_out;
  float* q_out    = out;                 // 8388608
  float* code_f   = out + 8388608;       // 8192
  float* vq       = out + 8396800;       // 1
  float* newemb   = out + 8396801;       // 524288
  float* newcount = out + 8921089;       // 8192

  float* ws = (float*)d_ws;
  float* hp_norm        = ws;                                  // 524288
  float* h2             = ws + 524288;                         // 8192
  float* E              = ws + 532480;                         // 524288
  float* e2             = ws + 1056768;                        // 8192
  unsigned short* hpH   = (unsigned short*)(ws + 1064960);     // 262144 f
  unsigned short* hpL   = (unsigned short*)(ws + 1327104);     // 262144 f
  unsigned short* EH    = (unsigned short*)(ws + 1589248);     // 262144 f
  unsigned short* EL    = (unsigned short*)(ws + 1851392);     // 262144 f
  float* amin_d         = ws + 2113536;                        // 32768
  int*   amin_c         = (int*)(ws + 2146304);                // 32768
  int*   code_i         = (int*)(ws + 2179072);                // 8192
  float* t5d            = ws + 2187264;                        // 163840
  int*   t5i            = (int*)(ws + 2351104);                // 163840
  float* loss_tok       = ws + 2514944;                        // 8192

  k_proj<<<1024, 256, 0, stream>>>(h, proj_w, proj_b, hp_norm, h2, hpH, hpL);
  k_enorm<<<2048, 256, 0, stream>>>(emb, E, e2, EH, EL);
  k_argmin<<<dim3(128, 4), 256, 0, stream>>>(hpH, hpL, EH, EL, h2, e2,
                                             amin_d, amin_c);
  k_top5<<<dim3(128, 4), 256, 0, stream>>>(hpH, hpL, EH, EL, h2, e2, mask,
                                           t5d, t5i);
  k_initcount<<<32, 256, 0, stream>>>(count, newcount);
  k_code<<<2048, 256, 0, stream>>>(amin_d, amin_c, hp_norm, E, mask,
                                   code_f, code_i, newcount, loss_tok);
  k_qout<<<512, 256, 0, stream>>>(code_i, hp_norm, E, proj_inv_w, proj_inv_b,
                                  q_out);
  k_emb<<<2048, 256, 0, stream>>>(t5d, t5i, hp_norm, E, newemb);
  k_vq<<<1, 256, 0, stream>>>(loss_tok, mask, vq);
}

// Round 4
// 234.712 us; speedup vs baseline: 3.9400x; 1.2915x over previous
//
#include <hip/hip_runtime.h>
#include <float.h>

// ---------------------------------------------------------------------------
// VQ layer forward, MI355X. B=4, L=2048 (8192 tokens), D=1024, VQ_DIM=64,
// K_CODES=8192, EMA_K=5.
// Round 4: k_proj rewritten as f32 tiled GEMM (16 tok x 64 dim x K=1024 per
// block, LDS-staged float4 operands). Round-3 k_proj was latency-bound on
// per-iteration scalar global loads of proj_w (VALUBusy 10%, 136 us).
// Distance kernels (MFMA bf16 hi/lo) unchanged from round 3.
// ---------------------------------------------------------------------------

typedef __attribute__((ext_vector_type(8)))  short bf16x8;   // 8 bf16 = 4 VGPR
typedef __attribute__((ext_vector_type(16))) float f32x16;   // MFMA 32x32 acc

__device__ __forceinline__ unsigned short f2bf(float x) {
  unsigned u = __float_as_uint(x);
  unsigned r = (u + 0x7fffu + ((u >> 16) & 1u)) >> 16;   // RNE
  return (unsigned short)r;
}
__device__ __forceinline__ float bf2f(unsigned short b) {
  return __uint_as_float(((unsigned)b) << 16);
}

// sorted-5 insert, plain strict < (ties keep existing = earlier/lower index)
__device__ __forceinline__ void tins5(float& d0, float& d1, float& d2,
                                      float& d3, float& d4, int& i0, int& i1,
                                      int& i2, int& i3, int& i4, float dv,
                                      int iv) {
  if (dv < d4) {
    d4 = dv; i4 = iv;
    if (d4 < d3) { float t = d3; d3 = d4; d4 = t; int u = i3; i3 = i4; i4 = u; }
    if (d3 < d2) { float t = d2; d2 = d3; d3 = t; int u = i2; i2 = i3; i3 = u; }
    if (d2 < d1) { float t = d1; d1 = d2; d2 = t; int u = i1; i1 = i2; i2 = u; }
    if (d1 < d0) { float t = d0; d0 = d1; d1 = t; int u = i0; i0 = i1; i1 = u; }
  }
}
// sorted-5 insert, lexicographic (d, idx) — for cross-lane/wave merges
__device__ __forceinline__ void lins5(float& d0, float& d1, float& d2,
                                      float& d3, float& d4, int& i0, int& i1,
                                      int& i2, int& i3, int& i4, float dv,
                                      int iv) {
  if (dv < d4 || (dv == d4 && iv < i4)) {
    d4 = dv; i4 = iv;
    if (d4 < d3 || (d4 == d3 && i4 < i3)) { float t = d3; d3 = d4; d4 = t; int u = i3; i3 = i4; i4 = u; }
    if (d3 < d2 || (d3 == d2 && i3 < i2)) { float t = d2; d2 = d3; d3 = t; int u = i2; i2 = i3; i3 = u; }
    if (d2 < d1 || (d2 == d1 && i2 < i1)) { float t = d1; d1 = d2; d2 = t; int u = i1; i1 = i2; i2 = u; }
    if (d1 < d0 || (d1 == d0 && i1 < i0)) { float t = d0; d0 = d1; d1 = t; int u = i0; i0 = i1; i1 = u; }
  }
}

// ---------------- Kernel 1: hp = normalize(h @ proj_w + b), + bf16 split ---
// Grid 512: 16 tokens/block, K=1024 in 16 chunks of 64 staged in LDS.
// Thread = (tok = tid>>4, dimg = tid&15 owning dims 4*dimg..4*dimg+3).
__global__ __launch_bounds__(256) void k_proj(
    const float* __restrict__ h, const float* __restrict__ w,
    const float* __restrict__ bias, float* __restrict__ hp_norm,
    float* __restrict__ h2, unsigned short* __restrict__ hpH,
    unsigned short* __restrict__ hpL) {
  __shared__ __align__(16) float hs[16 * 68];   // 16 tok x 64 k (pad 68)
  __shared__ __align__(16) float ws[64 * 64];   // 64 k x 64 dim
  const int tid = threadIdx.x;
  const int tb = blockIdx.x * 16;
  const int tok = tid >> 4;
  const int dimg = tid & 15;
  const float4* h4 = (const float4*)h;
  const float4* w4 = (const float4*)w;
  float4* ws4 = (float4*)ws;
  float4 acc = {0.f, 0.f, 0.f, 0.f};
  for (int ch = 0; ch < 16; ++ch) {
    __syncthreads();   // previous chunk's reads done
    // stage h chunk: 16 tok x 64 k = 256 float4, one per thread
    *(float4*)&hs[tok * 68 + dimg * 4] = h4[(size_t)(tb + tok) * 256 + ch * 16 + dimg];
    // stage w chunk: 64 k x 64 dim = 1024 float4, four per thread
#pragma unroll
    for (int i = 0; i < 4; ++i) {
      int idx = tid + i * 256;
      int k = idx >> 4, dq = idx & 15;
      ws4[k * 16 + dq] = w4[(size_t)(ch * 64 + k) * 16 + dq];
    }
    __syncthreads();
#pragma unroll 8
    for (int k = 0; k < 64; ++k) {
      float hv = hs[tok * 68 + k];                       // broadcast per 16 lanes
      float4 wv = *(const float4*)&ws[k * 64 + dimg * 4]; // conflict-free b128
      acc.x = fmaf(hv, wv.x, acc.x);
      acc.y = fmaf(hv, wv.y, acc.y);
      acc.z = fmaf(hv, wv.z, acc.z);
      acc.w = fmaf(hv, wv.w, acc.w);
    }
  }
  const float4 bv = ((const float4*)bias)[dimg];
  acc.x += bv.x; acc.y += bv.y; acc.z += bv.z; acc.w += bv.w;
  // row norm across the 16 lanes sharing this token (lanes tl*16..tl*16+15)
  float sq = acc.x * acc.x + acc.y * acc.y + acc.z * acc.z + acc.w * acc.w;
#pragma unroll
  for (int o = 1; o <= 8; o <<= 1) sq += __shfl_xor(sq, o, 64);
  float nrm = sqrtf(sq);
  float4 vn;
  vn.x = acc.x / nrm; vn.y = acc.y / nrm; vn.z = acc.z / nrm; vn.w = acc.w / nrm;
  ((float4*)hp_norm)[(size_t)(tb + tok) * 16 + dimg] = vn;
  // bf16 hi/lo split, packed stores (4 x u16 = 8 B)
  unsigned short hx = f2bf(vn.x), hy = f2bf(vn.y), hz = f2bf(vn.z), hw = f2bf(vn.w);
  uint2 hi_pack, lo_pack;
  hi_pack.x = (unsigned)hx | ((unsigned)hy << 16);
  hi_pack.y = (unsigned)hz | ((unsigned)hw << 16);
  lo_pack.x = (unsigned)f2bf(vn.x - bf2f(hx)) | ((unsigned)f2bf(vn.y - bf2f(hy)) << 16);
  lo_pack.y = (unsigned)f2bf(vn.z - bf2f(hz)) | ((unsigned)f2bf(vn.w - bf2f(hw)) << 16);
  size_t pidx = ((size_t)(tb + tok) * 64 + dimg * 4) >> 2;
  ((uint2*)hpH)[pidx] = hi_pack;
  ((uint2*)hpL)[pidx] = lo_pack;
  // h2 = sum(vn^2) (reference recomputes on normalized values)
  float s2 = vn.x * vn.x + vn.y * vn.y + vn.z * vn.z + vn.w * vn.w;
#pragma unroll
  for (int o = 1; o <= 8; o <<= 1) s2 += __shfl_xor(s2, o, 64);
  if (dimg == 0) h2[tb + tok] = s2;
}

// ---------------- Kernel 2: E = normalize(emb), e2, + bf16 split -----------
__global__ __launch_bounds__(256) void k_enorm(
    const float* __restrict__ emb, float* __restrict__ E,
    float* __restrict__ e2, unsigned short* __restrict__ EH,
    unsigned short* __restrict__ EL) {
  const int c = blockIdx.x * 4 + (threadIdx.x >> 6);
  const int lane = threadIdx.x & 63;
  float v = emb[(size_t)c * 64 + lane];
  float sq = v * v;
#pragma unroll
  for (int o = 32; o > 0; o >>= 1) sq += __shfl_xor(sq, o, 64);
  float vn = v / sqrtf(sq);
  size_t oidx = (size_t)c * 64 + lane;
  E[oidx] = vn;
  unsigned short hb = f2bf(vn);
  EH[oidx] = hb;
  EL[oidx] = f2bf(vn - bf2f(hb));
  float s2 = vn * vn;
#pragma unroll
  for (int o = 32; o > 0; o >>= 1) s2 += __shfl_xor(s2, o, 64);
  if (lane == 0) e2[c] = s2;
}

// ---------------- Kernel 3a: argmin over codes (MFMA) ----------------------
// grid (128 token-tiles, 4 code-strips). Block: 64 tokens resident in A-frags,
// streams 2048 codes in 32 chunks of 64. Wave w: rowg=w>>1 (token half),
// colg=w&1 (code half). MFMA 32x32x16 bf16: C col=lane&31,
// row=(reg&3)+8*(reg>>2)+4*(lane>>5). A: row=lane&31, k=(lane>>5)*8+i. B: dual.
__global__ __launch_bounds__(256, 2) void k_argmin(
    const unsigned short* __restrict__ hpH, const unsigned short* __restrict__ hpL,
    const unsigned short* __restrict__ EH, const unsigned short* __restrict__ EL,
    const float* __restrict__ h2g, const float* __restrict__ e2g,
    float* __restrict__ amin_d, int* __restrict__ amin_c) {
  __shared__ float mD[2][64];
  __shared__ int mC[2][64];
  const int tid = threadIdx.x;
  const int w = tid >> 6, lane = tid & 63;
  const int l31 = lane & 31, lh = lane >> 5;
  const int rowg = w >> 1, colg = w & 1;
  const int tok_base = blockIdx.x * 64;
  const int row_t = tok_base + rowg * 32 + l31;
  bf16x8 aH[4], aL[4];
#pragma unroll
  for (int ks = 0; ks < 4; ++ks) {
    aH[ks] = *(const bf16x8*)(hpH + (size_t)row_t * 64 + ks * 16 + lh * 8);
    aL[ks] = *(const bf16x8*)(hpL + (size_t)row_t * 64 + ks * 16 + lh * 8);
  }
  float h2r[16];
#pragma unroll
  for (int r = 0; r < 16; ++r) {
    int roff = (r & 3) + 8 * (r >> 2) + 4 * lh;
    h2r[r] = h2g[tok_base + rowg * 32 + roff];
  }
  float bd[16]; int bc[16];
#pragma unroll
  for (int r = 0; r < 16; ++r) { bd[r] = FLT_MAX; bc[r] = 0x7fffffff; }
  const int cstrip = blockIdx.y * 2048;
#pragma unroll 2
  for (int ch = 0; ch < 32; ++ch) {
    const int col_c = cstrip + ch * 64 + colg * 32 + l31;
    bf16x8 bH[4], bL[4];
#pragma unroll
    for (int ks = 0; ks < 4; ++ks) {
      bH[ks] = *(const bf16x8*)(EH + (size_t)col_c * 64 + ks * 16 + lh * 8);
      bL[ks] = *(const bf16x8*)(EL + (size_t)col_c * 64 + ks * 16 + lh * 8);
    }
    float e2c = e2g[col_c];
    f32x16 acc = {};
#pragma unroll
    for (int ks = 0; ks < 4; ++ks)
      acc = __builtin_amdgcn_mfma_f32_32x32x16_bf16(aL[ks], bL[ks], acc, 0, 0, 0);
#pragma unroll
    for (int ks = 0; ks < 4; ++ks)
      acc = __builtin_amdgcn_mfma_f32_32x32x16_bf16(aL[ks], bH[ks], acc, 0, 0, 0);
#pragma unroll
    for (int ks = 0; ks < 4; ++ks)
      acc = __builtin_amdgcn_mfma_f32_32x32x16_bf16(aH[ks], bL[ks], acc, 0, 0, 0);
#pragma unroll
    for (int ks = 0; ks < 4; ++ks)
      acc = __builtin_amdgcn_mfma_f32_32x32x16_bf16(aH[ks], bH[ks], acc, 0, 0, 0);
#pragma unroll
    for (int r = 0; r < 16; ++r) {
      float s = h2r[r] + e2c;               // ref order: (h2+e2) - 2*dot
      float d = fmaf(-2.f, acc[r], s);
      if (d < bd[r]) { bd[r] = d; bc[r] = col_c; }  // codes ascend: strict <
    }
  }
  // reduce over the 32 lanes of each half (same 16 rows, 32 different codes)
#pragma unroll
  for (int r = 0; r < 16; ++r) {
#pragma unroll
    for (int o = 1; o <= 16; o <<= 1) {
      float od = __shfl_xor(bd[r], o, 64);
      int oc = __shfl_xor(bc[r], o, 64);
      if (od < bd[r] || (od == bd[r] && oc < bc[r])) { bd[r] = od; bc[r] = oc; }
    }
  }
  if (l31 == 0) {   // lanes 0 and 32 hold the per-half winners
#pragma unroll
    for (int r = 0; r < 16; ++r) {
      int roff = (r & 3) + 8 * (r >> 2) + 4 * lh;
      mD[colg][rowg * 32 + roff] = bd[r];
      mC[colg][rowg * 32 + roff] = bc[r];
    }
  }
  __syncthreads();
  if (tid < 64) {
    float d0 = mD[0][tid], d1 = mD[1][tid];
    int c0 = mC[0][tid], c1 = mC[1][tid];
    if (d1 < d0 || (d1 == d0 && c1 < c0)) { d0 = d1; c0 = c1; }
    int t = tok_base + tid;
    amin_d[(size_t)t * 4 + blockIdx.y] = d0;
    amin_c[(size_t)t * 4 + blockIdx.y] = c0;
  }
}

// ---------------- Kernel 3b: top-5 tokens per code (MFMA) ------------------
// grid (128 code-tiles, 4 token-strips). Block: 64 codes resident in B-frags,
// streams 2048 tokens in 32 chunks of 64. Per-lane running sorted-5 for its
// fixed code column; lexicographic merges at the end.
__global__ __launch_bounds__(256, 2) void k_top5(
    const unsigned short* __restrict__ hpH, const unsigned short* __restrict__ hpL,
    const unsigned short* __restrict__ EH, const unsigned short* __restrict__ EL,
    const float* __restrict__ h2g, const float* __restrict__ e2g,
    const float* __restrict__ maskg,
    float* __restrict__ t5d, int* __restrict__ t5i) {
  __shared__ float At[2048], Bm[2048], C1[2048];
  __shared__ float sD[2][2][32][5];
  __shared__ int sI[2][2][32][5];
  const int tid = threadIdx.x;
  const int w = tid >> 6, lane = tid & 63;
  const int l31 = lane & 31, lh = lane >> 5;
  const int rowg = w >> 1, colg = w & 1;
  const int code_base = blockIdx.x * 64;
  const int col_c = code_base + colg * 32 + l31;
  const int tstrip = blockIdx.y * 2048;
#pragma unroll
  for (int i = 0; i < 8; ++i) {
    int t = tid + i * 256;
    float m = maskg[tstrip + t];
    At[t] = h2g[tstrip + t];
    Bm[t] = m;
    C1[t] = 1.0e7f * (1.f - m);
  }
  bf16x8 bH[4], bL[4];
#pragma unroll
  for (int ks = 0; ks < 4; ++ks) {
    bH[ks] = *(const bf16x8*)(EH + (size_t)col_c * 64 + ks * 16 + lh * 8);
    bL[ks] = *(const bf16x8*)(EL + (size_t)col_c * 64 + ks * 16 + lh * 8);
  }
  const float e2c = e2g[col_c];
  float td0 = FLT_MAX, td1 = FLT_MAX, td2 = FLT_MAX, td3 = FLT_MAX, td4 = FLT_MAX;
  int ti0 = 0x7fffffff, ti1 = 0x7fffffff, ti2 = 0x7fffffff, ti3 = 0x7fffffff,
      ti4 = 0x7fffffff;
  __syncthreads();
#pragma unroll 2
  for (int ch = 0; ch < 32; ++ch) {
    const int rowbase = ch * 64 + rowg * 32 + 4 * lh;   // strip-local
    const int row_t = tstrip + ch * 64 + rowg * 32 + l31;
    bf16x8 aH[4], aL[4];
#pragma unroll
    for (int ks = 0; ks < 4; ++ks) {
      aH[ks] = *(const bf16x8*)(hpH + (size_t)row_t * 64 + ks * 16 + lh * 8);
      aL[ks] = *(const bf16x8*)(hpL + (size_t)row_t * 64 + ks * 16 + lh * 8);
    }
    f32x16 acc = {};
#pragma unroll
    for (int ks = 0; ks < 4; ++ks)
      acc = __builtin_amdgcn_mfma_f32_32x32x16_bf16(aL[ks], bL[ks], acc, 0, 0, 0);
#pragma unroll
    for (int ks = 0; ks < 4; ++ks)
      acc = __builtin_amdgcn_mfma_f32_32x32x16_bf16(aL[ks], bH[ks], acc, 0, 0, 0);
#pragma unroll
    for (int ks = 0; ks < 4; ++ks)
      acc = __builtin_amdgcn_mfma_f32_32x32x16_bf16(aH[ks], bL[ks], acc, 0, 0, 0);
#pragma unroll
    for (int ks = 0; ks < 4; ++ks)
      acc = __builtin_amdgcn_mfma_f32_32x32x16_bf16(aH[ks], bH[ks], acc, 0, 0, 0);
    const int tok0 = tstrip + rowbase;
#pragma unroll
    for (int rq = 0; rq < 4; ++rq) {
      float2 a01 = *(const float2*)&At[rowbase + 8 * rq];
      float2 a23 = *(const float2*)&At[rowbase + 8 * rq + 2];
      float2 m01 = *(const float2*)&Bm[rowbase + 8 * rq];
      float2 m23 = *(const float2*)&Bm[rowbase + 8 * rq + 2];
      float2 c01 = *(const float2*)&C1[rowbase + 8 * rq];
      float2 c23 = *(const float2*)&C1[rowbase + 8 * rq + 2];
      float s, d;
      s = a01.x + e2c; d = fmaf(-2.f, acc[4 * rq + 0], s); d = fmaf(d, m01.x, c01.x);
      tins5(td0, td1, td2, td3, td4, ti0, ti1, ti2, ti3, ti4, d, tok0 + 8 * rq + 0);
      s = a01.y + e2c; d = fmaf(-2.f, acc[4 * rq + 1], s); d = fmaf(d, m01.y, c01.y);
      tins5(td0, td1, td2, td3, td4, ti0, ti1, ti2, ti3, ti4, d, tok0 + 8 * rq + 1);
      s = a23.x + e2c; d = fmaf(-2.f, acc[4 * rq + 2], s); d = fmaf(d, m23.x, c23.x);
      tins5(td0, td1, td2, td3, td4, ti0, ti1, ti2, ti3, ti4, d, tok0 + 8 * rq + 2);
      s = a23.y + e2c; d = fmaf(-2.f, acc[4 * rq + 3], s); d = fmaf(d, m23.y, c23.y);
      tins5(td0, td1, td2, td3, td4, ti0, ti1, ti2, ti3, ti4, d, tok0 + 8 * rq + 3);
    }
  }
  // merge lane <-> lane^32 (same code column, other row-half). Snapshot first.
  {
    float od0 = __shfl_xor(td0, 32, 64), od1 = __shfl_xor(td1, 32, 64),
          od2 = __shfl_xor(td2, 32, 64), od3 = __shfl_xor(td3, 32, 64),
          od4 = __shfl_xor(td4, 32, 64);
    int oi0 = __shfl_xor(ti0, 32, 64), oi1 = __shfl_xor(ti1, 32, 64),
        oi2 = __shfl_xor(ti2, 32, 64), oi3 = __shfl_xor(ti3, 32, 64),
        oi4 = __shfl_xor(ti4, 32, 64);
    lins5(td0, td1, td2, td3, td4, ti0, ti1, ti2, ti3, ti4, od0, oi0);
    lins5(td0, td1, td2, td3, td4, ti0, ti1, ti2, ti3, ti4, od1, oi1);
    lins5(td0, td1, td2, td3, td4, ti0, ti1, ti2, ti3, ti4, od2, oi2);
    lins5(td0, td1, td2, td3, td4, ti0, ti1, ti2, ti3, ti4, od3, oi3);
    lins5(td0, td1, td2, td3, td4, ti0, ti1, ti2, ti3, ti4, od4, oi4);
  }
  if (lane < 32) {
    sD[colg][rowg][l31][0] = td0; sD[colg][rowg][l31][1] = td1;
    sD[colg][rowg][l31][2] = td2; sD[colg][rowg][l31][3] = td3;
    sD[colg][rowg][l31][4] = td4;
    sI[colg][rowg][l31][0] = ti0; sI[colg][rowg][l31][1] = ti1;
    sI[colg][rowg][l31][2] = ti2; sI[colg][rowg][l31][3] = ti3;
    sI[colg][rowg][l31][4] = ti4;
  }
  __syncthreads();
  if (tid < 64) {
    int cg = tid >> 5, cl = tid & 31;
    float rd0 = sD[cg][0][cl][0], rd1 = sD[cg][0][cl][1], rd2 = sD[cg][0][cl][2],
          rd3 = sD[cg][0][cl][3], rd4 = sD[cg][0][cl][4];
    int ri0 = sI[cg][0][cl][0], ri1 = sI[cg][0][cl][1], ri2 = sI[cg][0][cl][2],
        ri3 = sI[cg][0][cl][3], ri4 = sI[cg][0][cl][4];
#pragma unroll
    for (int s = 0; s < 5; ++s) {
      lins5(rd0, rd1, rd2, rd3, rd4, ri0, ri1, ri2, ri3, ri4,
            sD[cg][1][cl][s], sI[cg][1][cl][s]);
    }
    int code = code_base + cg * 32 + cl;
    size_t gb = (size_t)code * 20 + (size_t)blockIdx.y * 5;
    t5d[gb + 0] = rd0; t5i[gb + 0] = ri0;
    t5d[gb + 1] = rd1; t5i[gb + 1] = ri1;
    t5d[gb + 2] = rd2; t5i[gb + 2] = ri2;
    t5d[gb + 3] = rd3; t5i[gb + 3] = ri3;
    t5d[gb + 4] = rd4; t5i[gb + 4] = ri4;
  }
}

// ---------------- init new_count = count -----------------------------------
__global__ void k_initcount(const float* __restrict__ cnt,
                            float* __restrict__ ncnt) {
  int i = blockIdx.x * 256 + threadIdx.x;
  ncnt[i] = cnt[i];
}

// ---------------- Kernel 4: merge argmin, code, histogram, token loss ------
__global__ __launch_bounds__(256) void k_code(
    const float* __restrict__ amin_d, const int* __restrict__ amin_c,
    const float* __restrict__ hp, const float* __restrict__ E,
    const float* __restrict__ maskg,
    float* __restrict__ code_f, int* __restrict__ code_i,
    float* __restrict__ newcount, float* __restrict__ loss_tok) {
  const int wid = threadIdx.x >> 6;
  const int lane = threadIdx.x & 63;
  const int t = blockIdx.x * 4 + wid;
  float d = FLT_MAX;
  int c = 0x7fffffff;
  if (lane < 4) {
    d = amin_d[(size_t)t * 4 + lane];
    c = amin_c[(size_t)t * 4 + lane];
  }
#pragma unroll
  for (int o = 1; o <= 2; o <<= 1) {
    float od = __shfl_xor(d, o, 64);
    int oc = __shfl_xor(c, o, 64);
    if (od < d || (od == d && oc < c)) { d = od; c = oc; }
  }
  c = __shfl(c, 0, 64);
  if (maskg[t] == 0.f) c = 0;   // masked row: all dists 1e7 -> argmin = 0
  float a = hp[(size_t)t * 64 + lane];
  float e = E[(size_t)c * 64 + lane];
  float q = a + (e - a);
  float df = a - q;
  float ad = fabsf(df);
  float l = ad < 1.f ? 0.5f * df * df : ad - 0.5f;
#pragma unroll
  for (int o = 32; o > 0; o >>= 1) l += __shfl_xor(l, o, 64);
  if (lane == 0) {
    code_f[t] = (float)c;
    code_i[t] = c;
    loss_tok[t] = l;
    atomicAdd(&newcount[c], 1.0f);
  }
}

// ---------------- Kernel 5: q_out = q_ste @ proj_inv_w + b -----------------
__global__ __launch_bounds__(256) void k_qout(
    const int* __restrict__ code_i, const float* __restrict__ hp,
    const float* __restrict__ E, const float* __restrict__ w,
    const float* __restrict__ bias, float* __restrict__ qout) {
  __shared__ float qs[16][64];
  const int tid = threadIdx.x;
  const int tb = blockIdx.x * 16;
#pragma unroll
  for (int i = 0; i < 4; ++i) {
    int idx = tid + i * 256;
    int t = idx >> 6, j = idx & 63;
    int c = code_i[tb + t];
    float a = hp[(size_t)(tb + t) * 64 + j];
    float e = E[(size_t)c * 64 + j];
    qs[t][j] = a + (e - a);
  }
  __syncthreads();
  float acc[16][4];
#pragma unroll
  for (int t = 0; t < 16; ++t)
#pragma unroll
    for (int j = 0; j < 4; ++j) acc[t][j] = 0.f;
  const float4* w4 = (const float4*)w;
  for (int k = 0; k < 64; ++k) {
    float4 wv = w4[k * 256 + tid];
#pragma unroll
    for (int t = 0; t < 16; ++t) {
      float q = qs[t][k];
      acc[t][0] = fmaf(q, wv.x, acc[t][0]);
      acc[t][1] = fmaf(q, wv.y, acc[t][1]);
      acc[t][2] = fmaf(q, wv.z, acc[t][2]);
      acc[t][3] = fmaf(q, wv.w, acc[t][3]);
    }
  }
  const float4 bv = ((const float4*)bias)[tid];
  float4* o4 = (float4*)qout;
#pragma unroll
  for (int t = 0; t < 16; ++t) {
    float4 r;
    r.x = acc[t][0] + bv.x; r.y = acc[t][1] + bv.y;
    r.z = acc[t][2] + bv.z; r.w = acc[t][3] + bv.w;
    o4[(size_t)(tb + t) * 256 + tid] = r;
  }
}

// ---------------- Kernel 6: merge 4 strip top5 lists, EMA update -----------
__global__ __launch_bounds__(256) void k_emb(
    const float* __restrict__ t5d, const int* __restrict__ t5i,
    const float* __restrict__ hp, const float* __restrict__ E,
    float* __restrict__ newemb) {
  const int wid = threadIdx.x >> 6;
  const int lane = threadIdx.x & 63;
  const int c = blockIdx.x * 4 + wid;
  float d = FLT_MAX;
  int idx = 0x7fffffff;
  if (lane < 20) {
    d = t5d[(size_t)c * 20 + lane];
    idx = t5i[(size_t)c * 20 + lane];
  }
  float seld[5]; int sel[5];
#pragma unroll
  for (int r = 0; r < 5; ++r) {
    float bd = d; int bi = idx;
#pragma unroll
    for (int o = 1; o <= 32; o <<= 1) {
      float od = __shfl_xor(bd, o, 64);
      int oi = __shfl_xor(bi, o, 64);
      if (od < bd || (od == bd && oi < bi)) { bd = od; bi = oi; }
    }
    seld[r] = bd; sel[r] = bi;
    if (idx == bi) d = FLT_MAX;   // token ids unique across strips
  }
  float m5 = fabsf(seld[0]);
#pragma unroll
  for (int r = 1; r < 5; ++r) m5 = fminf(m5, fabsf(seld[r]));
  float hf = 0.f;
#pragma unroll
  for (int r = 0; r < 5; ++r) hf += hp[(size_t)sel[r] * 64 + lane];
  hf = hf / 5.0f;
  float ev = E[(size_t)c * 64 + lane];
  float outv = (m5 > 0.1f) ? (ev * 0.995f + hf * (float)(1.0 - 0.995)) : ev;
  newemb[(size_t)c * 64 + lane] = outv;
}

// ---------------- Kernel 7: vq_loss ----------------------------------------
__global__ __launch_bounds__(256) void k_vq(
    const float* __restrict__ loss_tok, const float* __restrict__ maskg,
    float* __restrict__ vq) {
  __shared__ float S[256], M[256];
  const int tid = threadIdx.x;
  float s = 0.f, m = 0.f;
  const int base = tid * 32;
  for (int i = 0; i < 32; ++i) {
    float mm = maskg[base + i];
    s = fmaf(loss_tok[base + i], mm, s);
    m += mm;
  }
  S[tid] = s; M[tid] = m;
  __syncthreads();
  if (tid == 0) {
    float tot = 0.f;
    for (int b = 0; b < 4; ++b) {
      float sb = 0.f, mb = 0.f;
      for (int i = 0; i < 64; ++i) { sb += S[b * 64 + i]; mb += M[b * 64 + i]; }
      tot += sb / mb;
    }
    vq[0] = tot * 1.25f / 256.0f;
  }
}

// ---------------------------------------------------------------------------
extern "C" void kernel_launch(void* const* d_in, const int* in_sizes, int n_in,
                              void* d_out, int out_size, void* d_ws,
                              size_t ws_size, hipStream_t stream) {
  (void)in_sizes; (void)n_in; (void)out_size; (void)ws_size;
  const float* h          = (const float*)d_in[0];
  const float* mask       = (const float*)d_in[1];
  const float* proj_w     = (const float*)d_in[2];
  const float* proj_b     = (const float*)d_in[3];
  const float* proj_inv_w = (const float*)d_in[4];
  const float* proj_inv_b = (const float*)d_in[5];
  const float* emb        = (const float*)d_in[6];
  const float* count      = (const float*)d_in[7];

  float* out      = (float*)d_out;
  float* q_out    = out;                 // 8388608
  float* code_f   = out + 8388608;       // 8192
  float* vq       = out + 8396800;       // 1
  float* newemb   = out + 8396801;       // 524288
  float* newcount = out + 8921089;       // 8192

  float* ws = (float*)d_ws;
  float* hp_norm        = ws;                                  // 524288
  float* h2             = ws + 524288;                         // 8192
  float* E              = ws + 532480;                         // 524288
  float* e2             = ws + 1056768;                        // 8192
  unsigned short* hpH   = (unsigned short*)(ws + 1064960);     // 262144 f
  unsigned short* hpL   = (unsigned short*)(ws + 1327104);     // 262144 f
  unsigned short* EH    = (unsigned short*)(ws + 1589248);     // 262144 f
  unsigned short* EL    = (unsigned short*)(ws + 1851392);     // 262144 f
  float* amin_d         = ws + 2113536;                        // 32768
  int*   amin_c         = (int*)(ws + 2146304);                // 32768
  int*   code_i         = (int*)(ws + 2179072);                // 8192
  float* t5d            = ws + 2187264;                        // 163840
  int*   t5i            = (int*)(ws + 2351104);                // 163840
  float* loss_tok       = ws + 2514944;                        // 8192

  k_proj<<<512, 256, 0, stream>>>(h, proj_w, proj_b, hp_norm, h2, hpH, hpL);
  k_enorm<<<2048, 256, 0, stream>>>(emb, E, e2, EH, EL);
  k_argmin<<<dim3(128, 4), 256, 0, stream>>>(hpH, hpL, EH, EL, h2, e2,
                                             amin_d, amin_c);
  k_top5<<<dim3(128, 4), 256, 0, stream>>>(hpH, hpL, EH, EL, h2, e2, mask,
                                           t5d, t5i);
  k_initcount<<<32, 256, 0, stream>>>(count, newcount);
  k_code<<<2048, 256, 0, stream>>>(amin_d, amin_c, hp_norm, E, mask,
                                   code_f, code_i, newcount, loss_tok);
  k_qout<<<512, 256, 0, stream>>>(code_i, hp_norm, E, proj_inv_w, proj_inv_b,
                                  q_out);
  k_emb<<<2048, 256, 0, stream>>>(t5d, t5i, hp_norm, E, newemb);
  k_vq<<<1, 256, 0, stream>>>(loss_tok, mask, vq);
}

// Round 5
// 228.091 us; speedup vs baseline: 4.0544x; 1.0290x over previous
//
#include <hip/hip_runtime.h>
#include <float.h>

// ---------------------------------------------------------------------------
// VQ layer forward, MI355X. B=4, L=2048 (8192 tokens), D=1024, VQ_DIM=64,
// K_CODES=8192, EMA_K=5.
// Round 5: occupancy fix (8 strips, 1024 blocks) for both distance kernels +
// deferred LDS-buffered top-5 insertion in k_top5 (round-4 k_top5 burned
// ~25-30 predicated VALU ops per candidate in the sorted-5 chain; now ~6 ops
// filter + rare exact drains).
// ---------------------------------------------------------------------------

typedef __attribute__((ext_vector_type(8)))  short bf16x8;   // 8 bf16 = 4 VGPR
typedef __attribute__((ext_vector_type(16))) float f32x16;   // MFMA 32x32 acc

__device__ __forceinline__ unsigned short f2bf(float x) {
  unsigned u = __float_as_uint(x);
  unsigned r = (u + 0x7fffu + ((u >> 16) & 1u)) >> 16;   // RNE
  return (unsigned short)r;
}
__device__ __forceinline__ float bf2f(unsigned short b) {
  return __uint_as_float(((unsigned)b) << 16);
}

// sorted-5 insert, plain strict < (ties keep existing = earlier/lower index)
__device__ __forceinline__ void tins5(float& d0, float& d1, float& d2,
                                      float& d3, float& d4, int& i0, int& i1,
                                      int& i2, int& i3, int& i4, float dv,
                                      int iv) {
  if (dv < d4) {
    d4 = dv; i4 = iv;
    if (d4 < d3) { float t = d3; d3 = d4; d4 = t; int u = i3; i3 = i4; i4 = u; }
    if (d3 < d2) { float t = d2; d2 = d3; d3 = t; int u = i2; i2 = i3; i3 = u; }
    if (d2 < d1) { float t = d1; d1 = d2; d2 = t; int u = i1; i1 = i2; i2 = u; }
    if (d1 < d0) { float t = d0; d0 = d1; d1 = t; int u = i0; i0 = i1; i1 = u; }
  }
}
// sorted-5 insert, lexicographic (d, idx) — for cross-lane/wave merges
__device__ __forceinline__ void lins5(float& d0, float& d1, float& d2,
                                      float& d3, float& d4, int& i0, int& i1,
                                      int& i2, int& i3, int& i4, float dv,
                                      int iv) {
  if (dv < d4 || (dv == d4 && iv < i4)) {
    d4 = dv; i4 = iv;
    if (d4 < d3 || (d4 == d3 && i4 < i3)) { float t = d3; d3 = d4; d4 = t; int u = i3; i3 = i4; i4 = u; }
    if (d3 < d2 || (d3 == d2 && i3 < i2)) { float t = d2; d2 = d3; d3 = t; int u = i2; i2 = i3; i3 = u; }
    if (d2 < d1 || (d2 == d1 && i2 < i1)) { float t = d1; d1 = d2; d2 = t; int u = i1; i1 = i2; i2 = u; }
    if (d1 < d0 || (d1 == d0 && i1 < i0)) { float t = d0; d0 = d1; d1 = t; int u = i0; i0 = i1; i1 = u; }
  }
}

// ---------------- Kernel 1: hp = normalize(h @ proj_w + b), + bf16 split ---
__global__ __launch_bounds__(256) void k_proj(
    const float* __restrict__ h, const float* __restrict__ w,
    const float* __restrict__ bias, float* __restrict__ hp_norm,
    float* __restrict__ h2, unsigned short* __restrict__ hpH,
    unsigned short* __restrict__ hpL) {
  __shared__ __align__(16) float hs[16 * 68];   // 16 tok x 64 k (pad 68)
  __shared__ __align__(16) float ws[64 * 64];   // 64 k x 64 dim
  const int tid = threadIdx.x;
  const int tb = blockIdx.x * 16;
  const int tok = tid >> 4;
  const int dimg = tid & 15;
  const float4* h4 = (const float4*)h;
  const float4* w4 = (const float4*)w;
  float4* ws4 = (float4*)ws;
  float4 acc = {0.f, 0.f, 0.f, 0.f};
  for (int ch = 0; ch < 16; ++ch) {
    __syncthreads();   // previous chunk's reads done
    *(float4*)&hs[tok * 68 + dimg * 4] = h4[(size_t)(tb + tok) * 256 + ch * 16 + dimg];
#pragma unroll
    for (int i = 0; i < 4; ++i) {
      int idx = tid + i * 256;
      int k = idx >> 4, dq = idx & 15;
      ws4[k * 16 + dq] = w4[(size_t)(ch * 64 + k) * 16 + dq];
    }
    __syncthreads();
#pragma unroll 8
    for (int k = 0; k < 64; ++k) {
      float hv = hs[tok * 68 + k];
      float4 wv = *(const float4*)&ws[k * 64 + dimg * 4];
      acc.x = fmaf(hv, wv.x, acc.x);
      acc.y = fmaf(hv, wv.y, acc.y);
      acc.z = fmaf(hv, wv.z, acc.z);
      acc.w = fmaf(hv, wv.w, acc.w);
    }
  }
  const float4 bv = ((const float4*)bias)[dimg];
  acc.x += bv.x; acc.y += bv.y; acc.z += bv.z; acc.w += bv.w;
  float sq = acc.x * acc.x + acc.y * acc.y + acc.z * acc.z + acc.w * acc.w;
#pragma unroll
  for (int o = 1; o <= 8; o <<= 1) sq += __shfl_xor(sq, o, 64);
  float nrm = sqrtf(sq);
  float4 vn;
  vn.x = acc.x / nrm; vn.y = acc.y / nrm; vn.z = acc.z / nrm; vn.w = acc.w / nrm;
  ((float4*)hp_norm)[(size_t)(tb + tok) * 16 + dimg] = vn;
  unsigned short hx = f2bf(vn.x), hy = f2bf(vn.y), hz = f2bf(vn.z), hw = f2bf(vn.w);
  uint2 hi_pack, lo_pack;
  hi_pack.x = (unsigned)hx | ((unsigned)hy << 16);
  hi_pack.y = (unsigned)hz | ((unsigned)hw << 16);
  lo_pack.x = (unsigned)f2bf(vn.x - bf2f(hx)) | ((unsigned)f2bf(vn.y - bf2f(hy)) << 16);
  lo_pack.y = (unsigned)f2bf(vn.z - bf2f(hz)) | ((unsigned)f2bf(vn.w - bf2f(hw)) << 16);
  size_t pidx = ((size_t)(tb + tok) * 64 + dimg * 4) >> 2;
  ((uint2*)hpH)[pidx] = hi_pack;
  ((uint2*)hpL)[pidx] = lo_pack;
  float s2 = vn.x * vn.x + vn.y * vn.y + vn.z * vn.z + vn.w * vn.w;
#pragma unroll
  for (int o = 1; o <= 8; o <<= 1) s2 += __shfl_xor(s2, o, 64);
  if (dimg == 0) h2[tb + tok] = s2;
}

// ---------------- Kernel 2: E = normalize(emb), e2, + bf16 split -----------
__global__ __launch_bounds__(256) void k_enorm(
    const float* __restrict__ emb, float* __restrict__ E,
    float* __restrict__ e2, unsigned short* __restrict__ EH,
    unsigned short* __restrict__ EL) {
  const int c = blockIdx.x * 4 + (threadIdx.x >> 6);
  const int lane = threadIdx.x & 63;
  float v = emb[(size_t)c * 64 + lane];
  float sq = v * v;
#pragma unroll
  for (int o = 32; o > 0; o >>= 1) sq += __shfl_xor(sq, o, 64);
  float vn = v / sqrtf(sq);
  size_t oidx = (size_t)c * 64 + lane;
  E[oidx] = vn;
  unsigned short hb = f2bf(vn);
  EH[oidx] = hb;
  EL[oidx] = f2bf(vn - bf2f(hb));
  float s2 = vn * vn;
#pragma unroll
  for (int o = 32; o > 0; o >>= 1) s2 += __shfl_xor(s2, o, 64);
  if (lane == 0) e2[c] = s2;
}

// ---------------- Kernel 3a: argmin over codes (MFMA) ----------------------
// grid (128 token-tiles, 8 code-strips). 64 tokens resident in A-frags,
// streams 1024 codes in 16 chunks of 64.
__global__ __launch_bounds__(256, 3) void k_argmin(
    const unsigned short* __restrict__ hpH, const unsigned short* __restrict__ hpL,
    const unsigned short* __restrict__ EH, const unsigned short* __restrict__ EL,
    const float* __restrict__ h2g, const float* __restrict__ e2g,
    float* __restrict__ amin_d, int* __restrict__ amin_c) {
  __shared__ float mD[2][64];
  __shared__ int mC[2][64];
  const int tid = threadIdx.x;
  const int w = tid >> 6, lane = tid & 63;
  const int l31 = lane & 31, lh = lane >> 5;
  const int rowg = w >> 1, colg = w & 1;
  const int tok_base = blockIdx.x * 64;
  const int row_t = tok_base + rowg * 32 + l31;
  bf16x8 aH[4], aL[4];
#pragma unroll
  for (int ks = 0; ks < 4; ++ks) {
    aH[ks] = *(const bf16x8*)(hpH + (size_t)row_t * 64 + ks * 16 + lh * 8);
    aL[ks] = *(const bf16x8*)(hpL + (size_t)row_t * 64 + ks * 16 + lh * 8);
  }
  float h2r[16];
#pragma unroll
  for (int r = 0; r < 16; ++r) {
    int roff = (r & 3) + 8 * (r >> 2) + 4 * lh;
    h2r[r] = h2g[tok_base + rowg * 32 + roff];
  }
  float bd[16]; int bc[16];
#pragma unroll
  for (int r = 0; r < 16; ++r) { bd[r] = FLT_MAX; bc[r] = 0x7fffffff; }
  const int cstrip = blockIdx.y * 1024;
#pragma unroll 2
  for (int ch = 0; ch < 16; ++ch) {
    const int col_c = cstrip + ch * 64 + colg * 32 + l31;
    bf16x8 bH[4], bL[4];
#pragma unroll
    for (int ks = 0; ks < 4; ++ks) {
      bH[ks] = *(const bf16x8*)(EH + (size_t)col_c * 64 + ks * 16 + lh * 8);
      bL[ks] = *(const bf16x8*)(EL + (size_t)col_c * 64 + ks * 16 + lh * 8);
    }
    float e2c = e2g[col_c];
    f32x16 acc = {};
#pragma unroll
    for (int ks = 0; ks < 4; ++ks)
      acc = __builtin_amdgcn_mfma_f32_32x32x16_bf16(aL[ks], bL[ks], acc, 0, 0, 0);
#pragma unroll
    for (int ks = 0; ks < 4; ++ks)
      acc = __builtin_amdgcn_mfma_f32_32x32x16_bf16(aL[ks], bH[ks], acc, 0, 0, 0);
#pragma unroll
    for (int ks = 0; ks < 4; ++ks)
      acc = __builtin_amdgcn_mfma_f32_32x32x16_bf16(aH[ks], bL[ks], acc, 0, 0, 0);
#pragma unroll
    for (int ks = 0; ks < 4; ++ks)
      acc = __builtin_amdgcn_mfma_f32_32x32x16_bf16(aH[ks], bH[ks], acc, 0, 0, 0);
#pragma unroll
    for (int r = 0; r < 16; ++r) {
      float s = h2r[r] + e2c;               // ref order: (h2+e2) - 2*dot
      float d = fmaf(-2.f, acc[r], s);
      if (d < bd[r]) { bd[r] = d; bc[r] = col_c; }  // codes ascend: strict <
    }
  }
#pragma unroll
  for (int r = 0; r < 16; ++r) {
#pragma unroll
    for (int o = 1; o <= 16; o <<= 1) {
      float od = __shfl_xor(bd[r], o, 64);
      int oc = __shfl_xor(bc[r], o, 64);
      if (od < bd[r] || (od == bd[r] && oc < bc[r])) { bd[r] = od; bc[r] = oc; }
    }
  }
  if (l31 == 0) {
#pragma unroll
    for (int r = 0; r < 16; ++r) {
      int roff = (r & 3) + 8 * (r >> 2) + 4 * lh;
      mD[colg][rowg * 32 + roff] = bd[r];
      mC[colg][rowg * 32 + roff] = bc[r];
    }
  }
  __syncthreads();
  if (tid < 64) {
    float d0 = mD[0][tid], d1 = mD[1][tid];
    int c0 = mC[0][tid], c1 = mC[1][tid];
    if (d1 < d0 || (d1 == d0 && c1 < c0)) { d0 = d1; c0 = c1; }
    int t = tok_base + tid;
    amin_d[(size_t)t * 8 + blockIdx.y] = d0;
    amin_c[(size_t)t * 8 + blockIdx.y] = c0;
  }
}

// ---------------- Kernel 3b: top-5 tokens per code (MFMA, deferred insert) -
// grid (128 code-tiles, 8 token-strips). 64 codes resident in B-frags,
// streams 1024 tokens in 16 chunks of 64. Candidates passing the (stale)
// 5th-best threshold go to a per-lane LDS FIFO; drained exactly twice/chunk.
// Superset property + FIFO token order => result identical to online insert.
__global__ __launch_bounds__(256, 4) void k_top5(
    const unsigned short* __restrict__ hpH, const unsigned short* __restrict__ hpL,
    const unsigned short* __restrict__ EH, const unsigned short* __restrict__ EL,
    const float* __restrict__ h2g, const float* __restrict__ e2g,
    const float* __restrict__ maskg,
    float* __restrict__ t5d, int* __restrict__ t5i) {
  __shared__ float Pm[1024];           // h2*m + 1e7*(1-m)
  __shared__ float Mm[1024];           // m
  __shared__ float bufD[4][64][9];     // per-wave, per-lane FIFO (cap 8, pad 9)
  __shared__ int   bufI[4][64][9];
  __shared__ float sD[2][2][32][5];
  __shared__ int sI[2][2][32][5];
  const int tid = threadIdx.x;
  const int w = tid >> 6, lane = tid & 63;
  const int l31 = lane & 31, lh = lane >> 5;
  const int rowg = w >> 1, colg = w & 1;
  const int code_base = blockIdx.x * 64;
  const int col_c = code_base + colg * 32 + l31;
  const int tstrip = blockIdx.y * 1024;
#pragma unroll
  for (int i = 0; i < 4; ++i) {
    int t = tid + i * 256;
    float m = maskg[tstrip + t];
    Mm[t] = m;
    Pm[t] = fmaf(h2g[tstrip + t], m, 1.0e7f * (1.f - m));
  }
  bf16x8 bH[4], bL[4];
#pragma unroll
  for (int ks = 0; ks < 4; ++ks) {
    bH[ks] = *(const bf16x8*)(EH + (size_t)col_c * 64 + ks * 16 + lh * 8);
    bL[ks] = *(const bf16x8*)(EL + (size_t)col_c * 64 + ks * 16 + lh * 8);
  }
  const float e2c = e2g[col_c];
  float td0 = FLT_MAX, td1 = FLT_MAX, td2 = FLT_MAX, td3 = FLT_MAX, td4 = FLT_MAX;
  int ti0 = 0x7fffffff, ti1 = 0x7fffffff, ti2 = 0x7fffffff, ti3 = 0x7fffffff,
      ti4 = 0x7fffffff;
  int cnt = 0;
  auto drain = [&]() {
    int mx = cnt;
#pragma unroll
    for (int o = 1; o < 64; o <<= 1) mx = max(mx, __shfl_xor(mx, o, 64));
    for (int k = 0; k < mx; ++k) {
      float dv = (k < cnt) ? bufD[w][lane][k] : FLT_MAX;
      int iv = bufI[w][lane][k];
      tins5(td0, td1, td2, td3, td4, ti0, ti1, ti2, ti3, ti4, dv, iv);
    }
    cnt = 0;
  };
  __syncthreads();
  for (int ch = 0; ch < 16; ++ch) {
    const int row_t = tstrip + ch * 64 + rowg * 32 + l31;
    bf16x8 aH[4], aL[4];
#pragma unroll
    for (int ks = 0; ks < 4; ++ks) {
      aH[ks] = *(const bf16x8*)(hpH + (size_t)row_t * 64 + ks * 16 + lh * 8);
      aL[ks] = *(const bf16x8*)(hpL + (size_t)row_t * 64 + ks * 16 + lh * 8);
    }
    f32x16 acc = {};
#pragma unroll
    for (int ks = 0; ks < 4; ++ks)
      acc = __builtin_amdgcn_mfma_f32_32x32x16_bf16(aL[ks], bL[ks], acc, 0, 0, 0);
#pragma unroll
    for (int ks = 0; ks < 4; ++ks)
      acc = __builtin_amdgcn_mfma_f32_32x32x16_bf16(aL[ks], bH[ks], acc, 0, 0, 0);
#pragma unroll
    for (int ks = 0; ks < 4; ++ks)
      acc = __builtin_amdgcn_mfma_f32_32x32x16_bf16(aH[ks], bL[ks], acc, 0, 0, 0);
#pragma unroll
    for (int ks = 0; ks < 4; ++ks)
      acc = __builtin_amdgcn_mfma_f32_32x32x16_bf16(aH[ks], bH[ks], acc, 0, 0, 0);
    const int rowb = ch * 64 + rowg * 32 + 4 * lh;   // strip-local token base
#pragma unroll
    for (int half = 0; half < 2; ++half) {
#pragma unroll
      for (int rq2 = 0; rq2 < 2; ++rq2) {
        const int rq = half * 2 + rq2;
        float4 pv = *(const float4*)&Pm[rowb + 8 * rq];
        float4 mv = *(const float4*)&Mm[rowb + 8 * rq];
        const int tok0 = tstrip + rowb + 8 * rq;
        float u, d;
        u = fmaf(-2.f, acc[4 * rq + 0], e2c); d = fmaf(mv.x, u, pv.x);
        if (d < td4) { bufD[w][lane][cnt] = d; bufI[w][lane][cnt] = tok0 + 0; ++cnt; }
        u = fmaf(-2.f, acc[4 * rq + 1], e2c); d = fmaf(mv.y, u, pv.y);
        if (d < td4) { bufD[w][lane][cnt] = d; bufI[w][lane][cnt] = tok0 + 1; ++cnt; }
        u = fmaf(-2.f, acc[4 * rq + 2], e2c); d = fmaf(mv.z, u, pv.z);
        if (d < td4) { bufD[w][lane][cnt] = d; bufI[w][lane][cnt] = tok0 + 2; ++cnt; }
        u = fmaf(-2.f, acc[4 * rq + 3], e2c); d = fmaf(mv.w, u, pv.w);
        if (d < td4) { bufD[w][lane][cnt] = d; bufI[w][lane][cnt] = tok0 + 3; ++cnt; }
      }
      drain();   // cap 8 respected: at most 8 candidates per half-chunk
    }
  }
  // merge lane <-> lane^32 (same code column, other row-half). Snapshot first.
  {
    float od0 = __shfl_xor(td0, 32, 64), od1 = __shfl_xor(td1, 32, 64),
          od2 = __shfl_xor(td2, 32, 64), od3 = __shfl_xor(td3, 32, 64),
          od4 = __shfl_xor(td4, 32, 64);
    int oi0 = __shfl_xor(ti0, 32, 64), oi1 = __shfl_xor(ti1, 32, 64),
        oi2 = __shfl_xor(ti2, 32, 64), oi3 = __shfl_xor(ti3, 32, 64),
        oi4 = __shfl_xor(ti4, 32, 64);
    lins5(td0, td1, td2, td3, td4, ti0, ti1, ti2, ti3, ti4, od0, oi0);
    lins5(td0, td1, td2, td3, td4, ti0, ti1, ti2, ti3, ti4, od1, oi1);
    lins5(td0, td1, td2, td3, td4, ti0, ti1, ti2, ti3, ti4, od2, oi2);
    lins5(td0, td1, td2, td3, td4, ti0, ti1, ti2, ti3, ti4, od3, oi3);
    lins5(td0, td1, td2, td3, td4, ti0, ti1, ti2, ti3, ti4, od4, oi4);
  }
  if (lane < 32) {
    sD[colg][rowg][l31][0] = td0; sD[colg][rowg][l31][1] = td1;
    sD[colg][rowg][l31][2] = td2; sD[colg][rowg][l31][3] = td3;
    sD[colg][rowg][l31][4] = td4;
    sI[colg][rowg][l31][0] = ti0; sI[colg][rowg][l31][1] = ti1;
    sI[colg][rowg][l31][2] = ti2; sI[colg][rowg][l31][3] = ti3;
    sI[colg][rowg][l31][4] = ti4;
  }
  __syncthreads();
  if (tid < 64) {
    int cg = tid >> 5, cl = tid & 31;
    float rd0 = sD[cg][0][cl][0], rd1 = sD[cg][0][cl][1], rd2 = sD[cg][0][cl][2],
          rd3 = sD[cg][0][cl][3], rd4 = sD[cg][0][cl][4];
    int ri0 = sI[cg][0][cl][0], ri1 = sI[cg][0][cl][1], ri2 = sI[cg][0][cl][2],
        ri3 = sI[cg][0][cl][3], ri4 = sI[cg][0][cl][4];
#pragma unroll
    for (int s = 0; s < 5; ++s) {
      lins5(rd0, rd1, rd2, rd3, rd4, ri0, ri1, ri2, ri3, ri4,
            sD[cg][1][cl][s], sI[cg][1][cl][s]);
    }
    int code = code_base + cg * 32 + cl;
    size_t gb = (size_t)code * 40 + (size_t)blockIdx.y * 5;
    t5d[gb + 0] = rd0; t5i[gb + 0] = ri0;
    t5d[gb + 1] = rd1; t5i[gb + 1] = ri1;
    t5d[gb + 2] = rd2; t5i[gb + 2] = ri2;
    t5d[gb + 3] = rd3; t5i[gb + 3] = ri3;
    t5d[gb + 4] = rd4; t5i[gb + 4] = ri4;
  }
}

// ---------------- init new_count = count -----------------------------------
__global__ void k_initcount(const float* __restrict__ cnt,
                            float* __restrict__ ncnt) {
  int i = blockIdx.x * 256 + threadIdx.x;
  ncnt[i] = cnt[i];
}

// ---------------- Kernel 4: merge argmin, code, histogram, token loss ------
__global__ __launch_bounds__(256) void k_code(
    const float* __restrict__ amin_d, const int* __restrict__ amin_c,
    const float* __restrict__ hp, const float* __restrict__ E,
    const float* __restrict__ maskg,
    float* __restrict__ code_f, int* __restrict__ code_i,
    float* __restrict__ newcount, float* __restrict__ loss_tok) {
  const int wid = threadIdx.x >> 6;
  const int lane = threadIdx.x & 63;
  const int t = blockIdx.x * 4 + wid;
  float d = FLT_MAX;
  int c = 0x7fffffff;
  if (lane < 8) {
    d = amin_d[(size_t)t * 8 + lane];
    c = amin_c[(size_t)t * 8 + lane];
  }
#pragma unroll
  for (int o = 1; o <= 4; o <<= 1) {
    float od = __shfl_xor(d, o, 64);
    int oc = __shfl_xor(c, o, 64);
    if (od < d || (od == d && oc < c)) { d = od; c = oc; }
  }
  c = __shfl(c, 0, 64);
  if (maskg[t] == 0.f) c = 0;   // masked row: all dists 1e7 -> argmin = 0
  float a = hp[(size_t)t * 64 + lane];
  float e = E[(size_t)c * 64 + lane];
  float q = a + (e - a);
  float df = a - q;
  float ad = fabsf(df);
  float l = ad < 1.f ? 0.5f * df * df : ad - 0.5f;
#pragma unroll
  for (int o = 32; o > 0; o >>= 1) l += __shfl_xor(l, o, 64);
  if (lane == 0) {
    code_f[t] = (float)c;
    code_i[t] = c;
    loss_tok[t] = l;
    atomicAdd(&newcount[c], 1.0f);
  }
}

// ---------------- Kernel 5: q_out = q_ste @ proj_inv_w + b -----------------
__global__ __launch_bounds__(256) void k_qout(
    const int* __restrict__ code_i, const float* __restrict__ hp,
    const float* __restrict__ E, const float* __restrict__ w,
    const float* __restrict__ bias, float* __restrict__ qout) {
  __shared__ float qs[16][64];
  const int tid = threadIdx.x;
  const int tb = blockIdx.x * 16;
#pragma unroll
  for (int i = 0; i < 4; ++i) {
    int idx = tid + i * 256;
    int t = idx >> 6, j = idx & 63;
    int c = code_i[tb + t];
    float a = hp[(size_t)(tb + t) * 64 + j];
    float e = E[(size_t)c * 64 + j];
    qs[t][j] = a + (e - a);
  }
  __syncthreads();
  float acc[16][4];
#pragma unroll
  for (int t = 0; t < 16; ++t)
#pragma unroll
    for (int j = 0; j < 4; ++j) acc[t][j] = 0.f;
  const float4* w4 = (const float4*)w;
  for (int k = 0; k < 64; ++k) {
    float4 wv = w4[k * 256 + tid];
#pragma unroll
    for (int t = 0; t < 16; ++t) {
      float q = qs[t][k];
      acc[t][0] = fmaf(q, wv.x, acc[t][0]);
      acc[t][1] = fmaf(q, wv.y, acc[t][1]);
      acc[t][2] = fmaf(q, wv.z, acc[t][2]);
      acc[t][3] = fmaf(q, wv.w, acc[t][3]);
    }
  }
  const float4 bv = ((const float4*)bias)[tid];
  float4* o4 = (float4*)qout;
#pragma unroll
  for (int t = 0; t < 16; ++t) {
    float4 r;
    r.x = acc[t][0] + bv.x; r.y = acc[t][1] + bv.y;
    r.z = acc[t][2] + bv.z; r.w = acc[t][3] + bv.w;
    o4[(size_t)(tb + t) * 256 + tid] = r;
  }
}

// ---------------- Kernel 6: merge 8 strip top5 lists, EMA update -----------
__global__ __launch_bounds__(256) void k_emb(
    const float* __restrict__ t5d, const int* __restrict__ t5i,
    const float* __restrict__ hp, const float* __restrict__ E,
    float* __restrict__ newemb) {
  const int wid = threadIdx.x >> 6;
  const int lane = threadIdx.x & 63;
  const int c = blockIdx.x * 4 + wid;
  float d = FLT_MAX;
  int idx = 0x7fffffff;
  if (lane < 40) {
    d = t5d[(size_t)c * 40 + lane];
    idx = t5i[(size_t)c * 40 + lane];
  }
  float seld[5]; int sel[5];
#pragma unroll
  for (int r = 0; r < 5; ++r) {
    float bd = d; int bi = idx;
#pragma unroll
    for (int o = 1; o <= 32; o <<= 1) {
      float od = __shfl_xor(bd, o, 64);
      int oi = __shfl_xor(bi, o, 64);
      if (od < bd || (od == bd && oi < bi)) { bd = od; bi = oi; }
    }
    seld[r] = bd; sel[r] = bi;
    if (idx == bi) d = FLT_MAX;   // token ids unique across strips
  }
  float m5 = fabsf(seld[0]);
#pragma unroll
  for (int r = 1; r < 5; ++r) m5 = fminf(m5, fabsf(seld[r]));
  float hf = 0.f;
#pragma unroll
  for (int r = 0; r < 5; ++r) hf += hp[(size_t)sel[r] * 64 + lane];
  hf = hf / 5.0f;
  float ev = E[(size_t)c * 64 + lane];
  float outv = (m5 > 0.1f) ? (ev * 0.995f + hf * (float)(1.0 - 0.995)) : ev;
  newemb[(size_t)c * 64 + lane] = outv;
}

// ---------------- Kernel 7: vq_loss ----------------------------------------
__global__ __launch_bounds__(256) void k_vq(
    const float* __restrict__ loss_tok, const float* __restrict__ maskg,
    float* __restrict__ vq) {
  __shared__ float S[256], M[256];
  const int tid = threadIdx.x;
  float s = 0.f, m = 0.f;
  const int base = tid * 32;
  for (int i = 0; i < 32; ++i) {
    float mm = maskg[base + i];
    s = fmaf(loss_tok[base + i], mm, s);
    m += mm;
  }
  S[tid] = s; M[tid] = m;
  __syncthreads();
  if (tid == 0) {
    float tot = 0.f;
    for (int b = 0; b < 4; ++b) {
      float sb = 0.f, mb = 0.f;
      for (int i = 0; i < 64; ++i) { sb += S[b * 64 + i]; mb += M[b * 64 + i]; }
      tot += sb / mb;
    }
    vq[0] = tot * 1.25f / 256.0f;
  }
}

// ---------------------------------------------------------------------------
extern "C" void kernel_launch(void* const* d_in, const int* in_sizes, int n_in,
                              void* d_out, int out_size, void* d_ws,
                              size_t ws_size, hipStream_t stream) {
  (void)in_sizes; (void)n_in; (void)out_size; (void)ws_size;
  const float* h          = (const float*)d_in[0];
  const float* mask       = (const float*)d_in[1];
  const float* proj_w     = (const float*)d_in[2];
  const float* proj_b     = (const float*)d_in[3];
  const float* proj_inv_w = (const float*)d_in[4];
  const float* proj_inv_b = (const float*)d_in[5];
  const float* emb        = (const float*)d_in[6];
  const float* count      = (const float*)d_in[7];

  float* out      = (float*)d_out;
  float* q_out    = out;                 // 8388608
  float* code_f   = out + 8388608;       // 8192
  float* vq       = out + 8396800;       // 1
  float* newemb   = out + 8396801;       // 524288
  float* newcount = out + 8921089;       // 8192

  float* ws = (float*)d_ws;
  float* hp_norm        = ws;                                  // 524288
  float* h2             = ws + 524288;                         // 8192
  float* E              = ws + 532480;                         // 524288
  float* e2             = ws + 1056768;                        // 8192
  unsigned short* hpH   = (unsigned short*)(ws + 1064960);     // 262144 f
  unsigned short* hpL   = (unsigned short*)(ws + 1327104);     // 262144 f
  unsigned short* EH    = (unsigned short*)(ws + 1589248);     // 262144 f
  unsigned short* EL    = (unsigned short*)(ws + 1851392);     // 262144 f
  float* amin_d         = ws + 2113536;                        // 65536 (8192*8)
  int*   amin_c         = (int*)(ws + 2179072);                // 65536
  int*   code_i         = (int*)(ws + 2244608);                // 8192
  float* t5d            = ws + 2252800;                        // 327680 (8192*40)
  int*   t5i            = (int*)(ws + 2580480);                // 327680
  float* loss_tok       = ws + 2908160;                        // 8192

  k_proj<<<512, 256, 0, stream>>>(h, proj_w, proj_b, hp_norm, h2, hpH, hpL);
  k_enorm<<<2048, 256, 0, stream>>>(emb, E, e2, EH, EL);
  k_argmin<<<dim3(128, 8), 256, 0, stream>>>(hpH, hpL, EH, EL, h2, e2,
                                             amin_d, amin_c);
  k_top5<<<dim3(128, 8), 256, 0, stream>>>(hpH, hpL, EH, EL, h2, e2, mask,
                                           t5d, t5i);
  k_initcount<<<32, 256, 0, stream>>>(count, newcount);
  k_code<<<2048, 256, 0, stream>>>(amin_d, amin_c, hp_norm, E, mask,
                                   code_f, code_i, newcount, loss_tok);
  k_qout<<<512, 256, 0, stream>>>(code_i, hp_norm, E, proj_inv_w, proj_inv_b,
                                  q_out);
  k_emb<<<2048, 256, 0, stream>>>(t5d, t5i, hp_norm, E, newemb);
  k_vq<<<1, 256, 0, stream>>>(loss_tok, mask, vq);
}

// Round 6
// 222.852 us; speedup vs baseline: 4.1497x; 1.0235x over previous
//
#include <hip/hip_runtime.h>
#include <float.h>

// ---------------------------------------------------------------------------
// VQ layer forward, MI355X. B=4, L=2048 (8192 tokens), D=1024, VQ_DIM=64,
// K_CODES=8192, EMA_K=5.
// Round 6: (1) k_top5 drain: wave-max shfl chain (2x6 dependent ds-ops per
// chunk, ~500 serial cyc) -> __any ballot loop (~2 ops when empty).
// (2) k_qout -> MFMA: q_ste==E[code] forward, so gather EH/EL rows by code;
// proj_inv_w transposed to [n][k] bf16 hi/lo inside k_enorm. (3) launch
// fusion: initcount+wT in k_enorm, vq in k_emb (9 -> 7 launches).
// ---------------------------------------------------------------------------

typedef __attribute__((ext_vector_type(8)))  short bf16x8;   // 8 bf16 = 4 VGPR
typedef __attribute__((ext_vector_type(16))) float f32x16;   // MFMA 32x32 acc

__device__ __forceinline__ unsigned short f2bf(float x) {
  unsigned u = __float_as_uint(x);
  unsigned r = (u + 0x7fffu + ((u >> 16) & 1u)) >> 16;   // RNE
  return (unsigned short)r;
}
__device__ __forceinline__ float bf2f(unsigned short b) {
  return __uint_as_float(((unsigned)b) << 16);
}

// sorted-5 insert, plain strict < (ties keep existing = earlier/lower index)
__device__ __forceinline__ void tins5(float& d0, float& d1, float& d2,
                                      float& d3, float& d4, int& i0, int& i1,
                                      int& i2, int& i3, int& i4, float dv,
                                      int iv) {
  if (dv < d4) {
    d4 = dv; i4 = iv;
    if (d4 < d3) { float t = d3; d3 = d4; d4 = t; int u = i3; i3 = i4; i4 = u; }
    if (d3 < d2) { float t = d2; d2 = d3; d3 = t; int u = i2; i2 = i3; i3 = u; }
    if (d2 < d1) { float t = d1; d1 = d2; d2 = t; int u = i1; i1 = i2; i2 = u; }
    if (d1 < d0) { float t = d0; d0 = d1; d1 = t; int u = i0; i0 = i1; i1 = u; }
  }
}
// sorted-5 insert, lexicographic (d, idx) — for cross-lane/wave merges
__device__ __forceinline__ void lins5(float& d0, float& d1, float& d2,
                                      float& d3, float& d4, int& i0, int& i1,
                                      int& i2, int& i3, int& i4, float dv,
                                      int iv) {
  if (dv < d4 || (dv == d4 && iv < i4)) {
    d4 = dv; i4 = iv;
    if (d4 < d3 || (d4 == d3 && i4 < i3)) { float t = d3; d3 = d4; d4 = t; int u = i3; i3 = i4; i4 = u; }
    if (d3 < d2 || (d3 == d2 && i3 < i2)) { float t = d2; d2 = d3; d3 = t; int u = i2; i2 = i3; i3 = u; }
    if (d2 < d1 || (d2 == d1 && i2 < i1)) { float t = d1; d1 = d2; d2 = t; int u = i1; i1 = i2; i2 = u; }
    if (d1 < d0 || (d1 == d0 && i1 < i0)) { float t = d0; d0 = d1; d1 = t; int u = i0; i0 = i1; i1 = u; }
  }
}

// ---------------- Kernel 1: hp = normalize(h @ proj_w + b), + bf16 split ---
__global__ __launch_bounds__(256) void k_proj(
    const float* __restrict__ h, const float* __restrict__ w,
    const float* __restrict__ bias, float* __restrict__ hp_norm,
    float* __restrict__ h2, unsigned short* __restrict__ hpH,
    unsigned short* __restrict__ hpL) {
  __shared__ __align__(16) float hs[16 * 68];   // 16 tok x 64 k (pad 68)
  __shared__ __align__(16) float ws[64 * 64];   // 64 k x 64 dim
  const int tid = threadIdx.x;
  const int tb = blockIdx.x * 16;
  const int tok = tid >> 4;
  const int dimg = tid & 15;
  const float4* h4 = (const float4*)h;
  const float4* w4 = (const float4*)w;
  float4* ws4 = (float4*)ws;
  float4 acc = {0.f, 0.f, 0.f, 0.f};
  for (int ch = 0; ch < 16; ++ch) {
    __syncthreads();   // previous chunk's reads done
    *(float4*)&hs[tok * 68 + dimg * 4] = h4[(size_t)(tb + tok) * 256 + ch * 16 + dimg];
#pragma unroll
    for (int i = 0; i < 4; ++i) {
      int idx = tid + i * 256;
      int k = idx >> 4, dq = idx & 15;
      ws4[k * 16 + dq] = w4[(size_t)(ch * 64 + k) * 16 + dq];
    }
    __syncthreads();
#pragma unroll 8
    for (int k = 0; k < 64; ++k) {
      float hv = hs[tok * 68 + k];
      float4 wv = *(const float4*)&ws[k * 64 + dimg * 4];
      acc.x = fmaf(hv, wv.x, acc.x);
      acc.y = fmaf(hv, wv.y, acc.y);
      acc.z = fmaf(hv, wv.z, acc.z);
      acc.w = fmaf(hv, wv.w, acc.w);
    }
  }
  const float4 bv = ((const float4*)bias)[dimg];
  acc.x += bv.x; acc.y += bv.y; acc.z += bv.z; acc.w += bv.w;
  float sq = acc.x * acc.x + acc.y * acc.y + acc.z * acc.z + acc.w * acc.w;
#pragma unroll
  for (int o = 1; o <= 8; o <<= 1) sq += __shfl_xor(sq, o, 64);
  float nrm = sqrtf(sq);
  float4 vn;
  vn.x = acc.x / nrm; vn.y = acc.y / nrm; vn.z = acc.z / nrm; vn.w = acc.w / nrm;
  ((float4*)hp_norm)[(size_t)(tb + tok) * 16 + dimg] = vn;
  unsigned short hx = f2bf(vn.x), hy = f2bf(vn.y), hz = f2bf(vn.z), hw = f2bf(vn.w);
  uint2 hi_pack, lo_pack;
  hi_pack.x = (unsigned)hx | ((unsigned)hy << 16);
  hi_pack.y = (unsigned)hz | ((unsigned)hw << 16);
  lo_pack.x = (unsigned)f2bf(vn.x - bf2f(hx)) | ((unsigned)f2bf(vn.y - bf2f(hy)) << 16);
  lo_pack.y = (unsigned)f2bf(vn.z - bf2f(hz)) | ((unsigned)f2bf(vn.w - bf2f(hw)) << 16);
  size_t pidx = ((size_t)(tb + tok) * 64 + dimg * 4) >> 2;
  ((uint2*)hpH)[pidx] = hi_pack;
  ((uint2*)hpL)[pidx] = lo_pack;
  float s2 = vn.x * vn.x + vn.y * vn.y + vn.z * vn.z + vn.w * vn.w;
#pragma unroll
  for (int o = 1; o <= 8; o <<= 1) s2 += __shfl_xor(s2, o, 64);
  if (dimg == 0) h2[tb + tok] = s2;
}

// ---------------- Kernel 2: E-normalize + initcount + wT transpose ---------
// grid 2096: [0,2048) enorm, [2048,2080) newcount=count, [2080,2096) wT.
__global__ __launch_bounds__(256) void k_enorm(
    const float* __restrict__ emb, float* __restrict__ E,
    float* __restrict__ e2, unsigned short* __restrict__ EH,
    unsigned short* __restrict__ EL,
    const float* __restrict__ cnt, float* __restrict__ ncnt,
    const float* __restrict__ wiv, unsigned short* __restrict__ wTH,
    unsigned short* __restrict__ wTL) {
  __shared__ float tile[64][65];
  const int b = blockIdx.x;
  const int tid = threadIdx.x;
  if (b >= 2080) {               // transpose proj_inv_w [64][1024] -> [n][k]
    const int n0 = (b - 2080) * 64;
    const float4* w4 = (const float4*)wiv;
#pragma unroll
    for (int i = 0; i < 4; ++i) {
      int idx = tid + i * 256;
      int k = idx >> 4, nq = idx & 15;
      float4 v = w4[k * 256 + (n0 >> 2) + nq];
      tile[nq * 4 + 0][k] = v.x;
      tile[nq * 4 + 1][k] = v.y;
      tile[nq * 4 + 2][k] = v.z;
      tile[nq * 4 + 3][k] = v.w;
    }
    __syncthreads();
    const int n = tid >> 2;
    const int k0 = (tid & 3) * 16;
#pragma unroll
    for (int j = 0; j < 16; j += 4) {
      int k = k0 + j;
      float x0 = tile[n][k], x1 = tile[n][k + 1], x2 = tile[n][k + 2],
            x3 = tile[n][k + 3];
      unsigned short h0 = f2bf(x0), h1 = f2bf(x1), h2_ = f2bf(x2), h3 = f2bf(x3);
      uint2 hp_, lp_;
      hp_.x = (unsigned)h0 | ((unsigned)h1 << 16);
      hp_.y = (unsigned)h2_ | ((unsigned)h3 << 16);
      lp_.x = (unsigned)f2bf(x0 - bf2f(h0)) | ((unsigned)f2bf(x1 - bf2f(h1)) << 16);
      lp_.y = (unsigned)f2bf(x2 - bf2f(h2_)) | ((unsigned)f2bf(x3 - bf2f(h3)) << 16);
      *(uint2*)(wTH + (size_t)(n0 + n) * 64 + k) = hp_;
      *(uint2*)(wTL + (size_t)(n0 + n) * 64 + k) = lp_;
    }
    return;
  }
  if (b >= 2048) {               // new_count = count
    int i = (b - 2048) * 256 + tid;
    ncnt[i] = cnt[i];
    return;
  }
  const int c = b * 4 + (tid >> 6);
  const int lane = tid & 63;
  float v = emb[(size_t)c * 64 + lane];
  float sq = v * v;
#pragma unroll
  for (int o = 32; o > 0; o >>= 1) sq += __shfl_xor(sq, o, 64);
  float vn = v / sqrtf(sq);
  size_t oidx = (size_t)c * 64 + lane;
  E[oidx] = vn;
  unsigned short hb = f2bf(vn);
  EH[oidx] = hb;
  EL[oidx] = f2bf(vn - bf2f(hb));
  float s2 = vn * vn;
#pragma unroll
  for (int o = 32; o > 0; o >>= 1) s2 += __shfl_xor(s2, o, 64);
  if (lane == 0) e2[c] = s2;
}

// ---------------- Kernel 3a: argmin over codes (MFMA) ----------------------
__global__ __launch_bounds__(256, 3) void k_argmin(
    const unsigned short* __restrict__ hpH, const unsigned short* __restrict__ hpL,
    const unsigned short* __restrict__ EH, const unsigned short* __restrict__ EL,
    const float* __restrict__ h2g, const float* __restrict__ e2g,
    float* __restrict__ amin_d, int* __restrict__ amin_c) {
  __shared__ float mD[2][64];
  __shared__ int mC[2][64];
  const int tid = threadIdx.x;
  const int w = tid >> 6, lane = tid & 63;
  const int l31 = lane & 31, lh = lane >> 5;
  const int rowg = w >> 1, colg = w & 1;
  const int tok_base = blockIdx.x * 64;
  const int row_t = tok_base + rowg * 32 + l31;
  bf16x8 aH[4], aL[4];
#pragma unroll
  for (int ks = 0; ks < 4; ++ks) {
    aH[ks] = *(const bf16x8*)(hpH + (size_t)row_t * 64 + ks * 16 + lh * 8);
    aL[ks] = *(const bf16x8*)(hpL + (size_t)row_t * 64 + ks * 16 + lh * 8);
  }
  float h2r[16];
#pragma unroll
  for (int r = 0; r < 16; ++r) {
    int roff = (r & 3) + 8 * (r >> 2) + 4 * lh;
    h2r[r] = h2g[tok_base + rowg * 32 + roff];
  }
  float bd[16]; int bc[16];
#pragma unroll
  for (int r = 0; r < 16; ++r) { bd[r] = FLT_MAX; bc[r] = 0x7fffffff; }
  const int cstrip = blockIdx.y * 1024;
#pragma unroll 2
  for (int ch = 0; ch < 16; ++ch) {
    const int col_c = cstrip + ch * 64 + colg * 32 + l31;
    bf16x8 bH[4], bL[4];
#pragma unroll
    for (int ks = 0; ks < 4; ++ks) {
      bH[ks] = *(const bf16x8*)(EH + (size_t)col_c * 64 + ks * 16 + lh * 8);
      bL[ks] = *(const bf16x8*)(EL + (size_t)col_c * 64 + ks * 16 + lh * 8);
    }
    float e2c = e2g[col_c];
    f32x16 acc = {};
#pragma unroll
    for (int ks = 0; ks < 4; ++ks)
      acc = __builtin_amdgcn_mfma_f32_32x32x16_bf16(aL[ks], bL[ks], acc, 0, 0, 0);
#pragma unroll
    for (int ks = 0; ks < 4; ++ks)
      acc = __builtin_amdgcn_mfma_f32_32x32x16_bf16(aL[ks], bH[ks], acc, 0, 0, 0);
#pragma unroll
    for (int ks = 0; ks < 4; ++ks)
      acc = __builtin_amdgcn_mfma_f32_32x32x16_bf16(aH[ks], bL[ks], acc, 0, 0, 0);
#pragma unroll
    for (int ks = 0; ks < 4; ++ks)
      acc = __builtin_amdgcn_mfma_f32_32x32x16_bf16(aH[ks], bH[ks], acc, 0, 0, 0);
#pragma unroll
    for (int r = 0; r < 16; ++r) {
      float s = h2r[r] + e2c;               // ref order: (h2+e2) - 2*dot
      float d = fmaf(-2.f, acc[r], s);
      if (d < bd[r]) { bd[r] = d; bc[r] = col_c; }  // codes ascend: strict <
    }
  }
#pragma unroll
  for (int r = 0; r < 16; ++r) {
#pragma unroll
    for (int o = 1; o <= 16; o <<= 1) {
      float od = __shfl_xor(bd[r], o, 64);
      int oc = __shfl_xor(bc[r], o, 64);
      if (od < bd[r] || (od == bd[r] && oc < bc[r])) { bd[r] = od; bc[r] = oc; }
    }
  }
  if (l31 == 0) {
#pragma unroll
    for (int r = 0; r < 16; ++r) {
      int roff = (r & 3) + 8 * (r >> 2) + 4 * lh;
      mD[colg][rowg * 32 + roff] = bd[r];
      mC[colg][rowg * 32 + roff] = bc[r];
    }
  }
  __syncthreads();
  if (tid < 64) {
    float d0 = mD[0][tid], d1 = mD[1][tid];
    int c0 = mC[0][tid], c1 = mC[1][tid];
    if (d1 < d0 || (d1 == d0 && c1 < c0)) { d0 = d1; c0 = c1; }
    int t = tok_base + tid;
    amin_d[(size_t)t * 8 + blockIdx.y] = d0;
    amin_c[(size_t)t * 8 + blockIdx.y] = c0;
  }
}

// ---------------- Kernel 3b: top-5 tokens per code (MFMA, deferred insert) -
// grid (128 code-tiles, 8 token-strips). Ballot-loop drain (no shfl max).
__global__ __launch_bounds__(256, 4) void k_top5(
    const unsigned short* __restrict__ hpH, const unsigned short* __restrict__ hpL,
    const unsigned short* __restrict__ EH, const unsigned short* __restrict__ EL,
    const float* __restrict__ h2g, const float* __restrict__ e2g,
    const float* __restrict__ maskg,
    float* __restrict__ t5d, int* __restrict__ t5i) {
  __shared__ float Pm[1024];           // h2*m + 1e7*(1-m)
  __shared__ float Mm[1024];           // m
  __shared__ float bufD[4][64][9];     // per-wave, per-lane FIFO (cap 8, pad 9)
  __shared__ int   bufI[4][64][9];
  __shared__ float sD[2][2][32][5];
  __shared__ int sI[2][2][32][5];
  const int tid = threadIdx.x;
  const int w = tid >> 6, lane = tid & 63;
  const int l31 = lane & 31, lh = lane >> 5;
  const int rowg = w >> 1, colg = w & 1;
  const int code_base = blockIdx.x * 64;
  const int col_c = code_base + colg * 32 + l31;
  const int tstrip = blockIdx.y * 1024;
#pragma unroll
  for (int i = 0; i < 4; ++i) {
    int t = tid + i * 256;
    float m = maskg[tstrip + t];
    Mm[t] = m;
    Pm[t] = fmaf(h2g[tstrip + t], m, 1.0e7f * (1.f - m));
  }
  bf16x8 bH[4], bL[4];
#pragma unroll
  for (int ks = 0; ks < 4; ++ks) {
    bH[ks] = *(const bf16x8*)(EH + (size_t)col_c * 64 + ks * 16 + lh * 8);
    bL[ks] = *(const bf16x8*)(EL + (size_t)col_c * 64 + ks * 16 + lh * 8);
  }
  const float e2c = e2g[col_c];
  float td0 = FLT_MAX, td1 = FLT_MAX, td2 = FLT_MAX, td3 = FLT_MAX, td4 = FLT_MAX;
  int ti0 = 0x7fffffff, ti1 = 0x7fffffff, ti2 = 0x7fffffff, ti3 = 0x7fffffff,
      ti4 = 0x7fffffff;
  int cnt = 0;
  auto drain = [&]() {
    int k = 0;
    while (__any(k < cnt)) {            // 1 v_cmp per iter, exits when all done
      bool act = k < cnt;
      float dv = act ? bufD[w][lane][k] : FLT_MAX;
      int iv = act ? bufI[w][lane][k] : 0x7fffffff;
      tins5(td0, td1, td2, td3, td4, ti0, ti1, ti2, ti3, ti4, dv, iv);
      ++k;
    }
    cnt = 0;
  };
  __syncthreads();
  for (int ch = 0; ch < 16; ++ch) {
    const int row_t = tstrip + ch * 64 + rowg * 32 + l31;
    bf16x8 aH[4], aL[4];
#pragma unroll
    for (int ks = 0; ks < 4; ++ks) {
      aH[ks] = *(const bf16x8*)(hpH + (size_t)row_t * 64 + ks * 16 + lh * 8);
      aL[ks] = *(const bf16x8*)(hpL + (size_t)row_t * 64 + ks * 16 + lh * 8);
    }
    f32x16 acc = {};
#pragma unroll
    for (int ks = 0; ks < 4; ++ks)
      acc = __builtin_amdgcn_mfma_f32_32x32x16_bf16(aL[ks], bL[ks], acc, 0, 0, 0);
#pragma unroll
    for (int ks = 0; ks < 4; ++ks)
      acc = __builtin_amdgcn_mfma_f32_32x32x16_bf16(aL[ks], bH[ks], acc, 0, 0, 0);
#pragma unroll
    for (int ks = 0; ks < 4; ++ks)
      acc = __builtin_amdgcn_mfma_f32_32x32x16_bf16(aH[ks], bL[ks], acc, 0, 0, 0);
#pragma unroll
    for (int ks = 0; ks < 4; ++ks)
      acc = __builtin_amdgcn_mfma_f32_32x32x16_bf16(aH[ks], bH[ks], acc, 0, 0, 0);
    const int rowb = ch * 64 + rowg * 32 + 4 * lh;   // strip-local token base
#pragma unroll
    for (int half = 0; half < 2; ++half) {
#pragma unroll
      for (int rq2 = 0; rq2 < 2; ++rq2) {
        const int rq = half * 2 + rq2;
        float4 pv = *(const float4*)&Pm[rowb + 8 * rq];
        float4 mv = *(const float4*)&Mm[rowb + 8 * rq];
        const int tok0 = tstrip + rowb + 8 * rq;
        float u, d;
        u = fmaf(-2.f, acc[4 * rq + 0], e2c); d = fmaf(mv.x, u, pv.x);
        if (d < td4) { bufD[w][lane][cnt] = d; bufI[w][lane][cnt] = tok0 + 0; ++cnt; }
        u = fmaf(-2.f, acc[4 * rq + 1], e2c); d = fmaf(mv.y, u, pv.y);
        if (d < td4) { bufD[w][lane][cnt] = d; bufI[w][lane][cnt] = tok0 + 1; ++cnt; }
        u = fmaf(-2.f, acc[4 * rq + 2], e2c); d = fmaf(mv.z, u, pv.z);
        if (d < td4) { bufD[w][lane][cnt] = d; bufI[w][lane][cnt] = tok0 + 2; ++cnt; }
        u = fmaf(-2.f, acc[4 * rq + 3], e2c); d = fmaf(mv.w, u, pv.w);
        if (d < td4) { bufD[w][lane][cnt] = d; bufI[w][lane][cnt] = tok0 + 3; ++cnt; }
      }
      drain();   // cap 8 respected: at most 8 candidates per half-chunk
    }
  }
  // merge lane <-> lane^32 (same code column, other row-half). Snapshot first.
  {
    float od0 = __shfl_xor(td0, 32, 64), od1 = __shfl_xor(td1, 32, 64),
          od2 = __shfl_xor(td2, 32, 64), od3 = __shfl_xor(td3, 32, 64),
          od4 = __shfl_xor(td4, 32, 64);
    int oi0 = __shfl_xor(ti0, 32, 64), oi1 = __shfl_xor(ti1, 32, 64),
        oi2 = __shfl_xor(ti2, 32, 64), oi3 = __shfl_xor(ti3, 32, 64),
        oi4 = __shfl_xor(ti4, 32, 64);
    lins5(td0, td1, td2, td3, td4, ti0, ti1, ti2, ti3, ti4, od0, oi0);
    lins5(td0, td1, td2, td3, td4, ti0, ti1, ti2, ti3, ti4, od1, oi1);
    lins5(td0, td1, td2, td3, td4, ti0, ti1, ti2, ti3, ti4, od2, oi2);
    lins5(td0, td1, td2, td3, td4, ti0, ti1, ti2, ti3, ti4, od3, oi3);
    lins5(td0, td1, td2, td3, td4, ti0, ti1, ti2, ti3, ti4, od4, oi4);
  }
  if (lane < 32) {
    sD[colg][rowg][l31][0] = td0; sD[colg][rowg][l31][1] = td1;
    sD[colg][rowg][l31][2] = td2; sD[colg][rowg][l31][3] = td3;
    sD[colg][rowg][l31][4] = td4;
    sI[colg][rowg][l31][0] = ti0; sI[colg][rowg][l31][1] = ti1;
    sI[colg][rowg][l31][2] = ti2; sI[colg][rowg][l31][3] = ti3;
    sI[colg][rowg][l31][4] = ti4;
  }
  __syncthreads();
  if (tid < 64) {
    int cg = tid >> 5, cl = tid & 31;
    float rd0 = sD[cg][0][cl][0], rd1 = sD[cg][0][cl][1], rd2 = sD[cg][0][cl][2],
          rd3 = sD[cg][0][cl][3], rd4 = sD[cg][0][cl][4];
    int ri0 = sI[cg][0][cl][0], ri1 = sI[cg][0][cl][1], ri2 = sI[cg][0][cl][2],
        ri3 = sI[cg][0][cl][3], ri4 = sI[cg][0][cl][4];
#pragma unroll
    for (int s = 0; s < 5; ++s) {
      lins5(rd0, rd1, rd2, rd3, rd4, ri0, ri1, ri2, ri3, ri4,
            sD[cg][1][cl][s], sI[cg][1][cl][s]);
    }
    int code = code_base + cg * 32 + cl;
    size_t gb = (size_t)code * 40 + (size_t)blockIdx.y * 5;
    t5d[gb + 0] = rd0; t5i[gb + 0] = ri0;
    t5d[gb + 1] = rd1; t5i[gb + 1] = ri1;
    t5d[gb + 2] = rd2; t5i[gb + 2] = ri2;
    t5d[gb + 3] = rd3; t5i[gb + 3] = ri3;
    t5d[gb + 4] = rd4; t5i[gb + 4] = ri4;
  }
}

// ---------------- Kernel 4: merge argmin, code, histogram, token loss ------
__global__ __launch_bounds__(256) void k_code(
    const float* __restrict__ amin_d, const int* __restrict__ amin_c,
    const float* __restrict__ hp, const float* __restrict__ E,
    const float* __restrict__ maskg,
    float* __restrict__ code_f, int* __restrict__ code_i,
    float* __restrict__ newcount, float* __restrict__ loss_tok) {
  const int wid = threadIdx.x >> 6;
  const int lane = threadIdx.x & 63;
  const int t = blockIdx.x * 4 + wid;
  float d = FLT_MAX;
  int c = 0x7fffffff;
  if (lane < 8) {
    d = amin_d[(size_t)t * 8 + lane];
    c = amin_c[(size_t)t * 8 + lane];
  }
#pragma unroll
  for (int o = 1; o <= 4; o <<= 1) {
    float od = __shfl_xor(d, o, 64);
    int oc = __shfl_xor(c, o, 64);
    if (od < d || (od == d && oc < c)) { d = od; c = oc; }
  }
  c = __shfl(c, 0, 64);
  if (maskg[t] == 0.f) c = 0;   // masked row: all dists 1e7 -> argmin = 0
  float a = hp[(size_t)t * 64 + lane];
  float e = E[(size_t)c * 64 + lane];
  float q = a + (e - a);
  float df = a - q;
  float ad = fabsf(df);
  float l = ad < 1.f ? 0.5f * df * df : ad - 0.5f;
#pragma unroll
  for (int o = 32; o > 0; o >>= 1) l += __shfl_xor(l, o, 64);
  if (lane == 0) {
    code_f[t] = (float)c;
    code_i[t] = c;
    loss_tok[t] = l;
    atomicAdd(&newcount[c], 1.0f);
  }
}

// ---------------- Kernel 5: q_out = E[code] @ proj_inv_w + b (MFMA) --------
// grid (128 token-tiles, 16 col-strips of 64). A rows gathered by code.
__global__ __launch_bounds__(256, 3) void k_qout(
    const int* __restrict__ code_i,
    const unsigned short* __restrict__ EH, const unsigned short* __restrict__ EL,
    const unsigned short* __restrict__ wTH, const unsigned short* __restrict__ wTL,
    const float* __restrict__ bias, float* __restrict__ qout) {
  const int tid = threadIdx.x;
  const int w = tid >> 6, lane = tid & 63;
  const int l31 = lane & 31, lh = lane >> 5;
  const int rowg = w >> 1, colg = w & 1;
  const int tok_base = blockIdx.x * 64;
  const int col_base = blockIdx.y * 64;
  const int row_t = tok_base + rowg * 32 + l31;
  const int c = code_i[row_t];
  const int n = col_base + colg * 32 + l31;
  bf16x8 aH[4], aL[4], bH[4], bL[4];
#pragma unroll
  for (int ks = 0; ks < 4; ++ks) {
    aH[ks] = *(const bf16x8*)(EH + (size_t)c * 64 + ks * 16 + lh * 8);
    aL[ks] = *(const bf16x8*)(EL + (size_t)c * 64 + ks * 16 + lh * 8);
    bH[ks] = *(const bf16x8*)(wTH + (size_t)n * 64 + ks * 16 + lh * 8);
    bL[ks] = *(const bf16x8*)(wTL + (size_t)n * 64 + ks * 16 + lh * 8);
  }
  f32x16 acc = {};
#pragma unroll
  for (int ks = 0; ks < 4; ++ks)
    acc = __builtin_amdgcn_mfma_f32_32x32x16_bf16(aL[ks], bL[ks], acc, 0, 0, 0);
#pragma unroll
  for (int ks = 0; ks < 4; ++ks)
    acc = __builtin_amdgcn_mfma_f32_32x32x16_bf16(aL[ks], bH[ks], acc, 0, 0, 0);
#pragma unroll
  for (int ks = 0; ks < 4; ++ks)
    acc = __builtin_amdgcn_mfma_f32_32x32x16_bf16(aH[ks], bL[ks], acc, 0, 0, 0);
#pragma unroll
  for (int ks = 0; ks < 4; ++ks)
    acc = __builtin_amdgcn_mfma_f32_32x32x16_bf16(aH[ks], bH[ks], acc, 0, 0, 0);
  const float bc = bias[n];
#pragma unroll
  for (int r = 0; r < 16; ++r) {
    int row = rowg * 32 + (r & 3) + 8 * (r >> 2) + 4 * lh;
    qout[(size_t)(tok_base + row) * 1024 + n] = acc[r] + bc;
  }
}

// ---------------- Kernel 6: merge top5 + EMA update; block 2048 = vq_loss --
__global__ __launch_bounds__(256) void k_emb(
    const float* __restrict__ t5d, const int* __restrict__ t5i,
    const float* __restrict__ hp, const float* __restrict__ E,
    float* __restrict__ newemb,
    const float* __restrict__ loss_tok, const float* __restrict__ maskg,
    float* __restrict__ vq) {
  __shared__ float S[256], M[256];
  const int tid = threadIdx.x;
  if (blockIdx.x == 2048) {      // vq_loss reduction
    float s = 0.f, m = 0.f;
    const int base = tid * 32;
    for (int i = 0; i < 32; ++i) {
      float mm = maskg[base + i];
      s = fmaf(loss_tok[base + i], mm, s);
      m += mm;
    }
    S[tid] = s; M[tid] = m;
    __syncthreads();
    if (tid == 0) {
      float tot = 0.f;
      for (int b = 0; b < 4; ++b) {
        float sb = 0.f, mb = 0.f;
        for (int i = 0; i < 64; ++i) { sb += S[b * 64 + i]; mb += M[b * 64 + i]; }
        tot += sb / mb;
      }
      vq[0] = tot * 1.25f / 256.0f;
    }
    return;
  }
  const int wid = tid >> 6;
  const int lane = tid & 63;
  const int c = blockIdx.x * 4 + wid;
  float d = FLT_MAX;
  int idx = 0x7fffffff;
  if (lane < 40) {
    d = t5d[(size_t)c * 40 + lane];
    idx = t5i[(size_t)c * 40 + lane];
  }
  float seld[5]; int sel[5];
#pragma unroll
  for (int r = 0; r < 5; ++r) {
    float bd = d; int bi = idx;
#pragma unroll
    for (int o = 1; o <= 32; o <<= 1) {
      float od = __shfl_xor(bd, o, 64);
      int oi = __shfl_xor(bi, o, 64);
      if (od < bd || (od == bd && oi < bi)) { bd = od; bi = oi; }
    }
    seld[r] = bd; sel[r] = bi;
    if (idx == bi) d = FLT_MAX;   // token ids unique across strips
  }
  float m5 = fabsf(seld[0]);
#pragma unroll
  for (int r = 1; r < 5; ++r) m5 = fminf(m5, fabsf(seld[r]));
  float hf = 0.f;
#pragma unroll
  for (int r = 0; r < 5; ++r) hf += hp[(size_t)sel[r] * 64 + lane];
  hf = hf / 5.0f;
  float ev = E[(size_t)c * 64 + lane];
  float outv = (m5 > 0.1f) ? (ev * 0.995f + hf * (float)(1.0 - 0.995)) : ev;
  newemb[(size_t)c * 64 + lane] = outv;
}

// ---------------------------------------------------------------------------
extern "C" void kernel_launch(void* const* d_in, const int* in_sizes, int n_in,
                              void* d_out, int out_size, void* d_ws,
                              size_t ws_size, hipStream_t stream) {
  (void)in_sizes; (void)n_in; (void)out_size; (void)ws_size;
  const float* h          = (const float*)d_in[0];
  const float* mask       = (const float*)d_in[1];
  const float* proj_w     = (const float*)d_in[2];
  const float* proj_b     = (const float*)d_in[3];
  const float* proj_inv_w = (const float*)d_in[4];
  const float* proj_inv_b = (const float*)d_in[5];
  const float* emb        = (const float*)d_in[6];
  const float* count      = (const float*)d_in[7];

  float* out      = (float*)d_out;
  float* q_out    = out;                 // 8388608
  float* code_f   = out + 8388608;       // 8192
  float* vq       = out + 8396800;       // 1
  float* newemb   = out + 8396801;       // 524288
  float* newcount = out + 8921089;       // 8192

  float* ws = (float*)d_ws;
  float* hp_norm        = ws;                                  // 524288
  float* h2             = ws + 524288;                         // 8192
  float* E              = ws + 532480;                         // 524288
  float* e2             = ws + 1056768;                        // 8192
  unsigned short* hpH   = (unsigned short*)(ws + 1064960);     // 262144 f
  unsigned short* hpL   = (unsigned short*)(ws + 1327104);     // 262144 f
  unsigned short* EH    = (unsigned short*)(ws + 1589248);     // 262144 f
  unsigned short* EL    = (unsigned short*)(ws + 1851392);     // 262144 f
  unsigned short* wTH   = (unsigned short*)(ws + 2113536);     // 32768 f
  unsigned short* wTL   = (unsigned short*)(ws + 2146304);     // 32768 f
  float* amin_d         = ws + 2179072;                        // 65536 (8192*8)
  int*   amin_c         = (int*)(ws + 2244608);                // 65536
  int*   code_i         = (int*)(ws + 2310144);                // 8192
  float* t5d            = ws + 2318336;                        // 327680 (8192*40)
  int*   t5i            = (int*)(ws + 2646016);                // 327680
  float* loss_tok       = ws + 2973696;                        // 8192

  k_proj<<<512, 256, 0, stream>>>(h, proj_w, proj_b, hp_norm, h2, hpH, hpL);
  k_enorm<<<2096, 256, 0, stream>>>(emb, E, e2, EH, EL, count, newcount,
                                    proj_inv_w, wTH, wTL);
  k_argmin<<<dim3(128, 8), 256, 0, stream>>>(hpH, hpL, EH, EL, h2, e2,
                                             amin_d, amin_c);
  k_top5<<<dim3(128, 8), 256, 0, stream>>>(hpH, hpL, EH, EL, h2, e2, mask,
                                           t5d, t5i);
  k_code<<<2048, 256, 0, stream>>>(amin_d, amin_c, hp_norm, E, mask,
                                   code_f, code_i, newcount, loss_tok);
  k_qout<<<dim3(128, 16), 256, 0, stream>>>(code_i, EH, EL, wTH, wTL,
                                            proj_inv_b, q_out);
  k_emb<<<2049, 256, 0, stream>>>(t5d, t5i, hp_norm, E, newemb,
                                  loss_tok, mask, vq);
}